// Round 2
// baseline (1869.072 us; speedup 1.0000x reference)
//
#include <hip/hip_runtime.h>

// RWKV-6 style block on MI355X (gfx950).
// E=2048, H=32, S=64, L=1024, B=4.  Big GEMMs in bf16 MFMA (16x16x32).
// Workspace: ~155.5 MiB, lifetime-aliased regions.

#define E     2048
#define LL    1024
#define HHH   32
#define SSS   64
#define NBL   4096      // B*L
#define NBLE  8388608   // B*L*E

typedef short bf16x8 __attribute__((ext_vector_type(8)));
typedef float f32x4  __attribute__((ext_vector_type(4)));
using u16 = unsigned short;

__device__ __forceinline__ u16 f2b(float f) {
    union { float f; unsigned int u; } c; c.f = f;
    unsigned int u = c.u;
    unsigned int r = (u + 0x7fffu + ((u >> 16) & 1u)) >> 16;
    return (u16)r;
}
__device__ __forceinline__ float b2f(u16 b) {
    union { unsigned int u; float f; } c; c.u = ((unsigned int)b) << 16; return c.f;
}

__device__ __forceinline__ float wave_sum(float v) {
#pragma unroll
    for (int m = 32; m >= 1; m >>= 1) v += __shfl_xor(v, m, 64);
    return v;
}

// ---------------- elementwise / prep kernels ----------------

__global__ __launch_bounds__(256) void k_convert(const float* __restrict__ in,
                                                 u16* __restrict__ out, int n) {
    int i = (blockIdx.x * 256 + threadIdx.x) * 4;
    if (i >= n) return;
    float4 v = *reinterpret_cast<const float4*>(in + i);
    ushort4 o = make_ushort4(f2b(v.x), f2b(v.y), f2b(v.z), f2b(v.w));
    *reinterpret_cast<ushort4*>(out + i) = o;
}

// in (R,C) fp32 -> out (C,R) bf16
__global__ __launch_bounds__(256) void k_transpose(const float* __restrict__ in,
                                                   u16* __restrict__ out, int R, int C) {
    int i = blockIdx.x * 256 + threadIdx.x;
    if (i >= R * C) return;
    int r = i / C, c = i - r * C;
    out[c * R + r] = f2b(in[i]);
}

__global__ __launch_bounds__(256) void k_ln(const float* __restrict__ x,
                                            const float* __restrict__ w,
                                            const float* __restrict__ b,
                                            float* __restrict__ out) {
    int row = blockIdx.x, tid = threadIdx.x;
    const float* xr = x + (size_t)row * E + tid * 8;
    float4 v0 = *reinterpret_cast<const float4*>(xr);
    float4 v1 = *reinterpret_cast<const float4*>(xr + 4);
    float s = v0.x + v0.y + v0.z + v0.w + v1.x + v1.y + v1.z + v1.w;
    __shared__ float red[4];
    s = wave_sum(s);
    int wid = tid >> 6, lane = tid & 63;
    if (lane == 0) red[wid] = s;
    __syncthreads();
    float mean = (red[0] + red[1] + red[2] + red[3]) * (1.0f / E);
    __syncthreads();
    float q = 0.f;
    q += (v0.x - mean) * (v0.x - mean); q += (v0.y - mean) * (v0.y - mean);
    q += (v0.z - mean) * (v0.z - mean); q += (v0.w - mean) * (v0.w - mean);
    q += (v1.x - mean) * (v1.x - mean); q += (v1.y - mean) * (v1.y - mean);
    q += (v1.z - mean) * (v1.z - mean); q += (v1.w - mean) * (v1.w - mean);
    q = wave_sum(q);
    if (lane == 0) red[wid] = q;
    __syncthreads();
    float inv = rsqrtf((red[0] + red[1] + red[2] + red[3]) * (1.0f / E) + 1e-5f);
    int e = tid * 8;
    float4 w0 = *reinterpret_cast<const float4*>(w + e);
    float4 w1 = *reinterpret_cast<const float4*>(w + e + 4);
    float4 b0 = *reinterpret_cast<const float4*>(b + e);
    float4 b1 = *reinterpret_cast<const float4*>(b + e + 4);
    float4 o0, o1;
    o0.x = (v0.x - mean) * inv * w0.x + b0.x; o0.y = (v0.y - mean) * inv * w0.y + b0.y;
    o0.z = (v0.z - mean) * inv * w0.z + b0.z; o0.w = (v0.w - mean) * inv * w0.w + b0.w;
    o1.x = (v1.x - mean) * inv * w1.x + b1.x; o1.y = (v1.y - mean) * inv * w1.y + b1.y;
    o1.z = (v1.z - mean) * inv * w1.z + b1.z; o1.w = (v1.w - mean) * inv * w1.w + b1.w;
    float* op = out + (size_t)row * E + e;
    *reinterpret_cast<float4*>(op) = o0;
    *reinterpret_cast<float4*>(op + 4) = o1;
}

// mk = bf16(xa + sx*maa_x), sx recomputed inline (time-mix shift, state row 1)
__global__ __launch_bounds__(256) void k_mk(const float* __restrict__ xa,
                                            const float* __restrict__ state,
                                            const float* __restrict__ maa_x,
                                            u16* __restrict__ out) {
    int i = (blockIdx.x * 256 + threadIdx.x) * 4;
    if (i >= NBLE) return;
    int n = i >> 11, e = i & (E - 1);
    int l = n & (LL - 1), b = n >> 10;
    float4 cur = *reinterpret_cast<const float4*>(xa + i);
    float4 prev;
    if (l > 0) prev = *reinterpret_cast<const float4*>(xa + i - E);
    else       prev = *reinterpret_cast<const float4*>(state + (size_t)b * 66 * E + E + e);
    float4 m = *reinterpret_cast<const float4*>(maa_x + e);
    ushort4 o = make_ushort4(f2b(cur.x + (prev.x - cur.x) * m.x),
                             f2b(cur.y + (prev.y - cur.y) * m.y),
                             f2b(cur.z + (prev.z - cur.z) * m.z),
                             f2b(cur.w + (prev.w - cur.w) * m.w));
    *reinterpret_cast<ushort4*>(out + i) = o;
}

// channel-mix token shift (state row 0) + two mixes -> bf16
__global__ __launch_bounds__(256) void k_mix2(const float* __restrict__ xc,
                                              const float* __restrict__ state,
                                              const float* __restrict__ mk,
                                              const float* __restrict__ mr,
                                              u16* __restrict__ xk2,
                                              u16* __restrict__ xr2) {
    int i = (blockIdx.x * 256 + threadIdx.x) * 4;
    if (i >= NBLE) return;
    int n = i >> 11, e = i & (E - 1);
    int l = n & (LL - 1), b = n >> 10;
    float4 cur = *reinterpret_cast<const float4*>(xc + i);
    float4 prev;
    if (l > 0) prev = *reinterpret_cast<const float4*>(xc + i - E);
    else       prev = *reinterpret_cast<const float4*>(state + (size_t)b * 66 * E + e);
    float4 sx = make_float4(prev.x - cur.x, prev.y - cur.y, prev.z - cur.z, prev.w - cur.w);
    float4 k4 = *reinterpret_cast<const float4*>(mk + e);
    float4 r4 = *reinterpret_cast<const float4*>(mr + e);
    ushort4 ok = make_ushort4(f2b(cur.x + sx.x * k4.x), f2b(cur.y + sx.y * k4.y),
                              f2b(cur.z + sx.z * k4.z), f2b(cur.w + sx.w * k4.w));
    ushort4 orr = make_ushort4(f2b(cur.x + sx.x * r4.x), f2b(cur.y + sx.y * r4.y),
                               f2b(cur.z + sx.z * r4.z), f2b(cur.w + sx.w * r4.w));
    *reinterpret_cast<ushort4*>(xk2 + i) = ok;
    *reinterpret_cast<ushort4*>(xr2 + i) = orr;
}

// per-head groupnorm over S=64, *gn_w+gn_b, *g (bf16, in-place ok) -> bf16
__global__ __launch_bounds__(256) void k_gnorm(const float* __restrict__ wkv,
                                               const u16* __restrict__ g,
                                               const float* __restrict__ gw,
                                               const float* __restrict__ gb,
                                               u16* __restrict__ ogg) {
    int gidx = blockIdx.x * 4 + (threadIdx.x >> 6);
    int lane = threadIdx.x & 63;
    int n = gidx >> 5, h = gidx & 31;
    size_t base = (size_t)n * E + h * SSS;
    float v = wkv[base + lane];
    float mean = wave_sum(v) * (1.0f / SSS);
    float d = v - mean;
    float var = wave_sum(d * d) * (1.0f / SSS);
    float norm = d * rsqrtf(var + 1e-5f);
    int e = h * SSS + lane;
    float res = norm * gw[e] + gb[e];
    float gv = b2f(g[base + lane]);
    ogg[base + lane] = f2b(res * gv);
}

// ---------------- WKV sequential scan ----------------
// grid = B*H*2 (half-columns), block = 128.  r,k,v bf16; w,state fp32.
__global__ __launch_bounds__(128) void k_scan(const u16* __restrict__ Rb,
                                              const u16* __restrict__ Kb,
                                              const u16* __restrict__ Vb,
                                              const float* __restrict__ W,
                                              const float* __restrict__ state,
                                              const float* __restrict__ u,
                                              float* __restrict__ out) {
    int blk = blockIdx.x;
    int b = blk >> 6;
    int rem = blk & 63;
    int h = rem >> 1, jh = rem & 1;
    int tid = threadIdx.x;
    int jl = tid & 31;
    int j = jh * 32 + jl;
    int ig = tid >> 5;
    int i0 = ig * 16;
    float s[16], uu[16];
    const float* s0 = state + (size_t)b * 66 * E + 2 * E + h * (SSS * SSS);
#pragma unroll
    for (int ii = 0; ii < 16; ii++) {
        s[ii] = s0[(i0 + ii) * SSS + j];
        uu[ii] = u[h * SSS + i0 + ii];
    }
    __shared__ float part[4][32];
    size_t off = (size_t)b * LL * E + h * SSS;
    for (int t = 0; t < LL; t++, off += E) {
        float vj = b2f(Vb[off + j]);
        float acc = 0.f;
#pragma unroll
        for (int c = 0; c < 4; c++) {
            ushort4 rc = *reinterpret_cast<const ushort4*>(Rb + off + i0 + c * 4);
            ushort4 kc = *reinterpret_cast<const ushort4*>(Kb + off + i0 + c * 4);
            float4  wc = *reinterpret_cast<const float4*>(W + off + i0 + c * 4);
            int bi = c * 4;
            float a;
            a = b2f(kc.x) * vj; acc += b2f(rc.x) * fmaf(uu[bi + 0], a, s[bi + 0]); s[bi + 0] = fmaf(wc.x, s[bi + 0], a);
            a = b2f(kc.y) * vj; acc += b2f(rc.y) * fmaf(uu[bi + 1], a, s[bi + 1]); s[bi + 1] = fmaf(wc.y, s[bi + 1], a);
            a = b2f(kc.z) * vj; acc += b2f(rc.z) * fmaf(uu[bi + 2], a, s[bi + 2]); s[bi + 2] = fmaf(wc.z, s[bi + 2], a);
            a = b2f(kc.w) * vj; acc += b2f(rc.w) * fmaf(uu[bi + 3], a, s[bi + 3]); s[bi + 3] = fmaf(wc.w, s[bi + 3], a);
        }
        part[ig][jl] = acc;
        __syncthreads();
        if (tid < 32)
            out[off + jh * 32 + tid] = part[0][tid] + part[1][tid] + part[2][tid] + part[3][tid];
        __syncthreads();
    }
}

// ---------------- bf16 MFMA NT GEMM with fused epilogues ----------------
// C[M,N] = ep( A[M,K](bf16,row-major,lda) * Bw[N,K](bf16,row-major)^T )
// EP: 1 tanh(bf16) 2 xm(bf16; emat1=xa f32, emat2=state, evec=stack row)
//     3 decay(f32) 5 emat1+acc(f32) 6 sigmoid(f32) 7 relu^2(bf16)
//     8 emat1+emat2*acc(f32) 9 plain bf16 10 silu bf16
#define BK  32
#define LDP 40

template <int EP>
__global__ __launch_bounds__(256) void k_gemm(const u16* __restrict__ A, int lda,
                                              const u16* __restrict__ Bw,
                                              void* __restrict__ C,
                                              int M, int N, int K,
                                              const float* __restrict__ evec,
                                              const float* __restrict__ emat1,
                                              const float* __restrict__ emat2) {
    __shared__ u16 As[64 * LDP];
    __shared__ u16 Bs[64 * LDP];
    const int tid = threadIdx.x;
    const int m0 = blockIdx.y << 6, n0 = blockIdx.x << 6;
    const int srow = tid >> 2, skc = (tid & 3) << 3;
    const int lane = tid & 63, wv = tid >> 6;
    const int wr = (wv >> 1) << 5, wc = (wv & 1) << 5;
    const int lr = lane & 15, lq = lane >> 4;
    f32x4 acc[2][2];
#pragma unroll
    for (int a = 0; a < 2; a++)
#pragma unroll
        for (int bq = 0; bq < 2; bq++) acc[a][bq] = {0.f, 0.f, 0.f, 0.f};
    const u16* aptr = A + (size_t)(m0 + srow) * lda + skc;
    const u16* bptr = Bw + (size_t)(n0 + srow) * K + skc;
    const bool bvalid = (n0 + srow) < N;
    for (int k0 = 0; k0 < K; k0 += BK) {
        float4 av = *reinterpret_cast<const float4*>(aptr + k0);
        float4 bv = bvalid ? *reinterpret_cast<const float4*>(bptr + k0)
                           : make_float4(0.f, 0.f, 0.f, 0.f);
        __syncthreads();
        *reinterpret_cast<float4*>(As + srow * LDP + skc) = av;
        *reinterpret_cast<float4*>(Bs + srow * LDP + skc) = bv;
        __syncthreads();
        bf16x8 a0 = *reinterpret_cast<const bf16x8*>(As + (wr + lr) * LDP + lq * 8);
        bf16x8 a1 = *reinterpret_cast<const bf16x8*>(As + (wr + 16 + lr) * LDP + lq * 8);
        bf16x8 b0 = *reinterpret_cast<const bf16x8*>(Bs + (wc + lr) * LDP + lq * 8);
        bf16x8 b1 = *reinterpret_cast<const bf16x8*>(Bs + (wc + 16 + lr) * LDP + lq * 8);
        acc[0][0] = __builtin_amdgcn_mfma_f32_16x16x32_bf16(a0, b0, acc[0][0], 0, 0, 0);
        acc[0][1] = __builtin_amdgcn_mfma_f32_16x16x32_bf16(a0, b1, acc[0][1], 0, 0, 0);
        acc[1][0] = __builtin_amdgcn_mfma_f32_16x16x32_bf16(a1, b0, acc[1][0], 0, 0, 0);
        acc[1][1] = __builtin_amdgcn_mfma_f32_16x16x32_bf16(a1, b1, acc[1][1], 0, 0, 0);
    }
    const int gmb = m0 + wr + lq * 4;
    const int gnb = n0 + wc + lr;
#pragma unroll
    for (int mi = 0; mi < 2; mi++) {
#pragma unroll
        for (int ni = 0; ni < 2; ni++) {
            int gn = gnb + ni * 16;
            if (gn >= N) continue;
#pragma unroll
            for (int i = 0; i < 4; i++) {
                int gm = gmb + mi * 16 + i;
                size_t idx = (size_t)gm * N + gn;
                float v = acc[mi][ni][i];
                if constexpr (EP == 1) ((u16*)C)[idx] = f2b(tanhf(v));
                else if constexpr (EP == 2) {
                    int l = gm & (LL - 1), bb = gm >> 10;
                    float cur = emat1[idx];
                    float prev = (l > 0) ? emat1[idx - E]
                                         : emat2[(size_t)bb * 66 * E + E + gn];
                    ((u16*)C)[idx] = f2b(cur + (prev - cur) * (evec[gn] + v));
                }
                else if constexpr (EP == 3) ((float*)C)[idx] = expf(-expf(evec[gn] + v));
                else if constexpr (EP == 5) ((float*)C)[idx] = emat1[idx] + v;
                else if constexpr (EP == 6) ((float*)C)[idx] = 1.f / (1.f + expf(-v));
                else if constexpr (EP == 7) { float t = fmaxf(v, 0.f); ((u16*)C)[idx] = f2b(t * t); }
                else if constexpr (EP == 8) ((float*)C)[idx] = emat1[idx] + emat2[idx] * v;
                else if constexpr (EP == 9) ((u16*)C)[idx] = f2b(v);
                else if constexpr (EP == 10) { float sg = 1.f / (1.f + expf(-v)); ((u16*)C)[idx] = f2b(v * sg); }
            }
        }
    }
}

// ---------------- launch ----------------

extern "C" void kernel_launch(void* const* d_in, const int* in_sizes, int n_in,
                              void* d_out, int out_size, void* d_ws, size_t ws_size,
                              hipStream_t stream) {
    const float* x          = (const float*)d_in[0];
    const float* state      = (const float*)d_in[1];
    const float* ln1_w      = (const float*)d_in[2];
    const float* ln1_b      = (const float*)d_in[3];
    const float* ln2_w      = (const float*)d_in[4];
    const float* ln2_b      = (const float*)d_in[5];
    const float* maa_x      = (const float*)d_in[6];
    const float* maa_w1     = (const float*)d_in[7];
    const float* maa_w2     = (const float*)d_in[8];
    const float* maa_stack  = (const float*)d_in[9];
    const float* time_decay = (const float*)d_in[10];
    const float* td_w1      = (const float*)d_in[11];
    const float* td_w2      = (const float*)d_in[12];
    const float* u          = (const float*)d_in[13];
    const float* Wr         = (const float*)d_in[14];
    const float* Wk         = (const float*)d_in[15];
    const float* Wv         = (const float*)d_in[16];
    const float* Wg         = (const float*)d_in[17];
    const float* Wo         = (const float*)d_in[18];
    const float* gn_w       = (const float*)d_in[19];
    const float* gn_b       = (const float*)d_in[20];
    const float* ffn_k      = (const float*)d_in[21];
    const float* ffn_r      = (const float*)d_in[22];
    const float* Wfk        = (const float*)d_in[23];
    const float* Wfr        = (const float*)d_in[24];
    const float* Wfv        = (const float*)d_in[25];

    char* ws = (char*)d_ws;
    // lifetime-aliased regions (total ~155.5 MiB)
    float* R0 = (float*)(ws);                        // xa -> wkv -> x1   (32 MiB f32)
    float* R1 = (float*)(ws + 33554432);             // Wdecay -> xc -> rr (32 MiB f32)
    u16*   R2 = (u16*)(ws + 67108864);               // mk/xm slot -> xk2 (16 MiB bf16)
    u16*   R3 = (u16*)(ws + 83886080);               // Rb -> xr2
    u16*   R4 = (u16*)(ws + 100663296);              // Kb -> kk
    u16*   R5 = (u16*)(ws + 117440512);              // Vb
    u16*   R6 = (u16*)(ws + 134217728);              // g -> ogg
    u16*   WB = (u16*)(ws + 150994944);              // weight bf16 slot (8 MiB)
    u16*   Hx = (u16*)(ws + 159383552);              // tanh(mk@w1)  NBL x 160
    u16*   Ht = (u16*)(ws + 160694272);              // tanh(xw@td1) NBL x 64
    u16*  WT1 = (u16*)(ws + 161218560);              // maa_w1^T  160 x 2048
    u16*  WT2 = (u16*)(ws + 161873920);              // maa_w2^T  5 x (2048 x 32)
    u16*  WT3 = (u16*)(ws + 162529280);              // td_w1^T   64 x 2048
    u16*  WT4 = (u16*)(ws + 162791424);              // td_w2^T   2048 x 64

    dim3 blk(256);
    dim3 g2048(32, 64), g160(3, 64), g64(1, 64);
    const int ncv = (E * E / 4) / 256;
    const int nel = NBLE / 1024;

    // small-weight transposes (to (N,K) bf16)
    k_transpose<<<(E * 160 + 255) / 256, blk, 0, stream>>>(maa_w1, WT1, E, 160);
    for (int f = 0; f < 5; f++)
        k_transpose<<<(32 * E + 255) / 256, blk, 0, stream>>>(maa_w2 + f * 32 * E, WT2 + f * E * 32, 32, E);
    k_transpose<<<(E * 64 + 255) / 256, blk, 0, stream>>>(td_w1, WT3, E, 64);
    k_transpose<<<(64 * E + 255) / 256, blk, 0, stream>>>(td_w2, WT4, 64, E);

    // time-mix front end
    k_ln<<<NBL, blk, 0, stream>>>(x, ln1_w, ln1_b, R0);                    // xa
    k_mk<<<nel, blk, 0, stream>>>(R0, state, maa_x, R2);                   // mk bf16
    k_gemm<1><<<g160, blk, 0, stream>>>(R2, E, WT1, Hx, NBL, 160, E, nullptr, nullptr, nullptr);

    // decay chain (f=1: w)
    k_gemm<2><<<g2048, blk, 0, stream>>>(Hx + 1 * 32, 160, WT2 + 1 * E * 32, R2,
                                         NBL, E, 32, maa_stack + 1 * E, R0, state);
    k_gemm<1><<<g64, blk, 0, stream>>>(R2, E, WT3, Ht, NBL, 64, E, nullptr, nullptr, nullptr);
    k_gemm<3><<<g2048, blk, 0, stream>>>(Ht, 64, WT4, R1, NBL, E, 64, time_decay, nullptr, nullptr);

    // k projection (f=0)
    k_gemm<2><<<g2048, blk, 0, stream>>>(Hx + 0 * 32, 160, WT2 + 0 * E * 32, R2,
                                         NBL, E, 32, maa_stack + 0 * E, R0, state);
    k_convert<<<ncv, blk, 0, stream>>>(Wk, WB, E * E);
    k_gemm<9><<<g2048, blk, 0, stream>>>(R2, E, WB, R4, NBL, E, E, nullptr, nullptr, nullptr);

    // v projection (f=2)
    k_gemm<2><<<g2048, blk, 0, stream>>>(Hx + 2 * 32, 160, WT2 + 2 * E * 32, R2,
                                         NBL, E, 32, maa_stack + 2 * E, R0, state);
    k_convert<<<ncv, blk, 0, stream>>>(Wv, WB, E * E);
    k_gemm<9><<<g2048, blk, 0, stream>>>(R2, E, WB, R5, NBL, E, E, nullptr, nullptr, nullptr);

    // g projection (f=4)
    k_gemm<2><<<g2048, blk, 0, stream>>>(Hx + 4 * 32, 160, WT2 + 4 * E * 32, R2,
                                         NBL, E, 32, maa_stack + 4 * E, R0, state);
    k_convert<<<ncv, blk, 0, stream>>>(Wg, WB, E * E);
    k_gemm<10><<<g2048, blk, 0, stream>>>(R2, E, WB, R6, NBL, E, E, nullptr, nullptr, nullptr);

    // r projection (f=3) — last use of xa (R0)
    k_gemm<2><<<g2048, blk, 0, stream>>>(Hx + 3 * 32, 160, WT2 + 3 * E * 32, R2,
                                         NBL, E, 32, maa_stack + 3 * E, R0, state);
    k_convert<<<ncv, blk, 0, stream>>>(Wr, WB, E * E);
    k_gemm<9><<<g2048, blk, 0, stream>>>(R2, E, WB, R3, NBL, E, E, nullptr, nullptr, nullptr);

    // sequential WKV scan -> R0 (wkv f32), then groupnorm * g -> ogg (R6 in place)
    k_scan<<<256, dim3(128), 0, stream>>>(R3, R4, R5, R1, state, u, R0);
    k_gnorm<<<NBL * HHH / 4, blk, 0, stream>>>(R0, R6, gn_w, gn_b, R6);

    // output projection + residual -> x1 (R0; wkv dead)
    k_convert<<<ncv, blk, 0, stream>>>(Wo, WB, E * E);
    k_gemm<5><<<g2048, blk, 0, stream>>>(R6, E, WB, R0, NBL, E, E, nullptr, x, nullptr);

    // channel mix
    k_ln<<<NBL, blk, 0, stream>>>(R0, ln2_w, ln2_b, R1);                   // xc
    k_mix2<<<nel, blk, 0, stream>>>(R1, state, ffn_k, ffn_r, R2, R3);      // xk2, xr2
    k_convert<<<ncv, blk, 0, stream>>>(Wfk, WB, E * E);
    k_gemm<7><<<g2048, blk, 0, stream>>>(R2, E, WB, R4, NBL, E, E, nullptr, nullptr, nullptr);
    k_convert<<<ncv, blk, 0, stream>>>(Wfr, WB, E * E);
    k_gemm<6><<<g2048, blk, 0, stream>>>(R3, E, WB, R1, NBL, E, E, nullptr, nullptr, nullptr);
    k_convert<<<ncv, blk, 0, stream>>>(Wfv, WB, E * E);
    k_gemm<8><<<g2048, blk, 0, stream>>>(R4, E, WB, (float*)d_out, NBL, E, E, nullptr, R0, R1);
}

// Round 3
// 1263.820 us; speedup vs baseline: 1.4789x; 1.4789x over previous
//
#include <hip/hip_runtime.h>

// RWKV-6 style block on MI355X (gfx950).
// E=2048, H=32, S=64, L=1024, B=4.
// Round 3: m97-style 128-tile global_load_lds GEMM for all N=2048 GEMMs,
//          restructured 1-barrier prefetched WKV scan.

#define E     2048
#define LL    1024
#define HHH   32
#define SSS   64
#define NBL   4096      // B*L
#define NBLE  8388608   // B*L*E

typedef short bf16x8 __attribute__((ext_vector_type(8)));
typedef float f32x4  __attribute__((ext_vector_type(4)));
using u16 = unsigned short;

__device__ __forceinline__ u16 f2b(float f) {
    union { float f; unsigned int u; } c; c.f = f;
    unsigned int u = c.u;
    unsigned int r = (u + 0x7fffu + ((u >> 16) & 1u)) >> 16;
    return (u16)r;
}
__device__ __forceinline__ float b2f(u16 b) {
    union { unsigned int u; float f; } c; c.u = ((unsigned int)b) << 16; return c.f;
}

__device__ __forceinline__ float wave_sum(float v) {
#pragma unroll
    for (int m = 32; m >= 1; m >>= 1) v += __shfl_xor(v, m, 64);
    return v;
}

__device__ __forceinline__ void gl_lds16(const u16* g, u16* l) {
    __builtin_amdgcn_global_load_lds((const __attribute__((address_space(1))) unsigned int*)g,
                                     (__attribute__((address_space(3))) unsigned int*)l, 16, 0, 0);
}

// ---------------- elementwise / prep kernels ----------------

__global__ __launch_bounds__(256) void k_convert(const float* __restrict__ in,
                                                 u16* __restrict__ out, int n) {
    int i = (blockIdx.x * 256 + threadIdx.x) * 4;
    if (i >= n) return;
    float4 v = *reinterpret_cast<const float4*>(in + i);
    ushort4 o = make_ushort4(f2b(v.x), f2b(v.y), f2b(v.z), f2b(v.w));
    *reinterpret_cast<ushort4*>(out + i) = o;
}

// in (R,C) fp32 -> out (C,R) bf16
__global__ __launch_bounds__(256) void k_transpose(const float* __restrict__ in,
                                                   u16* __restrict__ out, int R, int C) {
    int i = blockIdx.x * 256 + threadIdx.x;
    if (i >= R * C) return;
    int r = i / C, c = i - r * C;
    out[c * R + r] = f2b(in[i]);
}

__global__ __launch_bounds__(256) void k_ln(const float* __restrict__ x,
                                            const float* __restrict__ w,
                                            const float* __restrict__ b,
                                            float* __restrict__ out) {
    int row = blockIdx.x, tid = threadIdx.x;
    const float* xr = x + (size_t)row * E + tid * 8;
    float4 v0 = *reinterpret_cast<const float4*>(xr);
    float4 v1 = *reinterpret_cast<const float4*>(xr + 4);
    float s = v0.x + v0.y + v0.z + v0.w + v1.x + v1.y + v1.z + v1.w;
    __shared__ float red[4];
    s = wave_sum(s);
    int wid = tid >> 6, lane = tid & 63;
    if (lane == 0) red[wid] = s;
    __syncthreads();
    float mean = (red[0] + red[1] + red[2] + red[3]) * (1.0f / E);
    __syncthreads();
    float q = 0.f;
    q += (v0.x - mean) * (v0.x - mean); q += (v0.y - mean) * (v0.y - mean);
    q += (v0.z - mean) * (v0.z - mean); q += (v0.w - mean) * (v0.w - mean);
    q += (v1.x - mean) * (v1.x - mean); q += (v1.y - mean) * (v1.y - mean);
    q += (v1.z - mean) * (v1.z - mean); q += (v1.w - mean) * (v1.w - mean);
    q = wave_sum(q);
    if (lane == 0) red[wid] = q;
    __syncthreads();
    float inv = rsqrtf((red[0] + red[1] + red[2] + red[3]) * (1.0f / E) + 1e-5f);
    int e = tid * 8;
    float4 w0 = *reinterpret_cast<const float4*>(w + e);
    float4 w1 = *reinterpret_cast<const float4*>(w + e + 4);
    float4 b0 = *reinterpret_cast<const float4*>(b + e);
    float4 b1 = *reinterpret_cast<const float4*>(b + e + 4);
    float4 o0, o1;
    o0.x = (v0.x - mean) * inv * w0.x + b0.x; o0.y = (v0.y - mean) * inv * w0.y + b0.y;
    o0.z = (v0.z - mean) * inv * w0.z + b0.z; o0.w = (v0.w - mean) * inv * w0.w + b0.w;
    o1.x = (v1.x - mean) * inv * w1.x + b1.x; o1.y = (v1.y - mean) * inv * w1.y + b1.y;
    o1.z = (v1.z - mean) * inv * w1.z + b1.z; o1.w = (v1.w - mean) * inv * w1.w + b1.w;
    float* op = out + (size_t)row * E + e;
    *reinterpret_cast<float4*>(op) = o0;
    *reinterpret_cast<float4*>(op + 4) = o1;
}

// mk = bf16(xa + sx*maa_x), sx recomputed inline (time-mix shift, state row 1)
__global__ __launch_bounds__(256) void k_mk(const float* __restrict__ xa,
                                            const float* __restrict__ state,
                                            const float* __restrict__ maa_x,
                                            u16* __restrict__ out) {
    int i = (blockIdx.x * 256 + threadIdx.x) * 4;
    if (i >= NBLE) return;
    int n = i >> 11, e = i & (E - 1);
    int l = n & (LL - 1), b = n >> 10;
    float4 cur = *reinterpret_cast<const float4*>(xa + i);
    float4 prev;
    if (l > 0) prev = *reinterpret_cast<const float4*>(xa + i - E);
    else       prev = *reinterpret_cast<const float4*>(state + (size_t)b * 66 * E + E + e);
    float4 m = *reinterpret_cast<const float4*>(maa_x + e);
    ushort4 o = make_ushort4(f2b(cur.x + (prev.x - cur.x) * m.x),
                             f2b(cur.y + (prev.y - cur.y) * m.y),
                             f2b(cur.z + (prev.z - cur.z) * m.z),
                             f2b(cur.w + (prev.w - cur.w) * m.w));
    *reinterpret_cast<ushort4*>(out + i) = o;
}

// channel-mix token shift (state row 0) + two mixes -> bf16
__global__ __launch_bounds__(256) void k_mix2(const float* __restrict__ xc,
                                              const float* __restrict__ state,
                                              const float* __restrict__ mk,
                                              const float* __restrict__ mr,
                                              u16* __restrict__ xk2,
                                              u16* __restrict__ xr2) {
    int i = (blockIdx.x * 256 + threadIdx.x) * 4;
    if (i >= NBLE) return;
    int n = i >> 11, e = i & (E - 1);
    int l = n & (LL - 1), b = n >> 10;
    float4 cur = *reinterpret_cast<const float4*>(xc + i);
    float4 prev;
    if (l > 0) prev = *reinterpret_cast<const float4*>(xc + i - E);
    else       prev = *reinterpret_cast<const float4*>(state + (size_t)b * 66 * E + e);
    float4 sx = make_float4(prev.x - cur.x, prev.y - cur.y, prev.z - cur.z, prev.w - cur.w);
    float4 k4 = *reinterpret_cast<const float4*>(mk + e);
    float4 r4 = *reinterpret_cast<const float4*>(mr + e);
    ushort4 ok = make_ushort4(f2b(cur.x + sx.x * k4.x), f2b(cur.y + sx.y * k4.y),
                              f2b(cur.z + sx.z * k4.z), f2b(cur.w + sx.w * k4.w));
    ushort4 orr = make_ushort4(f2b(cur.x + sx.x * r4.x), f2b(cur.y + sx.y * r4.y),
                               f2b(cur.z + sx.z * r4.z), f2b(cur.w + sx.w * r4.w));
    *reinterpret_cast<ushort4*>(xk2 + i) = ok;
    *reinterpret_cast<ushort4*>(xr2 + i) = orr;
}

// per-head groupnorm over S=64, *gn_w+gn_b, *g (bf16, in-place ok) -> bf16
__global__ __launch_bounds__(256) void k_gnorm(const float* __restrict__ wkv,
                                               const u16* __restrict__ g,
                                               const float* __restrict__ gw,
                                               const float* __restrict__ gb,
                                               u16* __restrict__ ogg) {
    int gidx = blockIdx.x * 4 + (threadIdx.x >> 6);
    int lane = threadIdx.x & 63;
    int n = gidx >> 5, h = gidx & 31;
    size_t base = (size_t)n * E + h * SSS;
    float v = wkv[base + lane];
    float mean = wave_sum(v) * (1.0f / SSS);
    float d = v - mean;
    float var = wave_sum(d * d) * (1.0f / SSS);
    float norm = d * rsqrtf(var + 1e-5f);
    int e = h * SSS + lane;
    float res = norm * gw[e] + gb[e];
    float gv = b2f(g[base + lane]);
    ogg[base + lane] = f2b(res * gv);
}

// ---------------- WKV sequential scan ----------------
// grid = B*H*2 = 256 blocks (j half-split), 256 threads (i split 8-way).
// One barrier per timestep (double-buffered LDS partials), next-step loads
// prefetched before the barrier.  r,k,v bf16; w,state,acc fp32.
__global__ __launch_bounds__(256) void k_scan(const u16* __restrict__ Rb,
                                              const u16* __restrict__ Kb,
                                              const u16* __restrict__ Vb,
                                              const float* __restrict__ W,
                                              const float* __restrict__ state,
                                              const float* __restrict__ u,
                                              float* __restrict__ out) {
    int blk = blockIdx.x;
    int b = blk >> 6;
    int rem = blk & 63;
    int h = rem >> 1, jh = rem & 1;
    int tid = threadIdx.x;
    int jl = tid & 31;
    int j = jh * 32 + jl;
    int ig = tid >> 5;          // 0..7
    int i0 = ig * 8;
    float s[8], uu[8];
    const float* s0 = state + (size_t)b * 66 * E + 2 * E + h * (SSS * SSS);
#pragma unroll
    for (int ii = 0; ii < 8; ii++) {
        s[ii] = s0[(i0 + ii) * SSS + j];
        uu[ii] = u[h * SSS + i0 + ii];
    }
    __shared__ float part[2][8][32];
    size_t off = (size_t)b * LL * E + h * SSS;
    // prefetch t=0
    ushort4 pr0 = *reinterpret_cast<const ushort4*>(Rb + off + i0);
    ushort4 pr1 = *reinterpret_cast<const ushort4*>(Rb + off + i0 + 4);
    ushort4 pk0 = *reinterpret_cast<const ushort4*>(Kb + off + i0);
    ushort4 pk1 = *reinterpret_cast<const ushort4*>(Kb + off + i0 + 4);
    float4  pw0 = *reinterpret_cast<const float4*>(W + off + i0);
    float4  pw1 = *reinterpret_cast<const float4*>(W + off + i0 + 4);
    u16     pv  = Vb[off + j];
    for (int t = 0; t < LL; t++) {
        ushort4 cr0 = pr0, cr1 = pr1, ck0 = pk0, ck1 = pk1;
        float4 cw0 = pw0, cw1 = pw1;
        u16 cv = pv;
        size_t off2 = off + E;
        // prefetch t+1 (last iter reads <4KB past logical end, still inside ws)
        pr0 = *reinterpret_cast<const ushort4*>(Rb + off2 + i0);
        pr1 = *reinterpret_cast<const ushort4*>(Rb + off2 + i0 + 4);
        pk0 = *reinterpret_cast<const ushort4*>(Kb + off2 + i0);
        pk1 = *reinterpret_cast<const ushort4*>(Kb + off2 + i0 + 4);
        pw0 = *reinterpret_cast<const float4*>(W + off2 + i0);
        pw1 = *reinterpret_cast<const float4*>(W + off2 + i0 + 4);
        pv  = Vb[off2 + j];
        float vj = b2f(cv);
        float acc = 0.f, a;
        a = b2f(ck0.x) * vj; acc += b2f(cr0.x) * fmaf(uu[0], a, s[0]); s[0] = fmaf(cw0.x, s[0], a);
        a = b2f(ck0.y) * vj; acc += b2f(cr0.y) * fmaf(uu[1], a, s[1]); s[1] = fmaf(cw0.y, s[1], a);
        a = b2f(ck0.z) * vj; acc += b2f(cr0.z) * fmaf(uu[2], a, s[2]); s[2] = fmaf(cw0.z, s[2], a);
        a = b2f(ck0.w) * vj; acc += b2f(cr0.w) * fmaf(uu[3], a, s[3]); s[3] = fmaf(cw0.w, s[3], a);
        a = b2f(ck1.x) * vj; acc += b2f(cr1.x) * fmaf(uu[4], a, s[4]); s[4] = fmaf(cw1.x, s[4], a);
        a = b2f(ck1.y) * vj; acc += b2f(cr1.y) * fmaf(uu[5], a, s[5]); s[5] = fmaf(cw1.y, s[5], a);
        a = b2f(ck1.z) * vj; acc += b2f(cr1.z) * fmaf(uu[6], a, s[6]); s[6] = fmaf(cw1.z, s[6], a);
        a = b2f(ck1.w) * vj; acc += b2f(cr1.w) * fmaf(uu[7], a, s[7]); s[7] = fmaf(cw1.w, s[7], a);
        part[t & 1][ig][jl] = acc;
        __syncthreads();
        if (tid < 32) {
            const float* p = &part[t & 1][0][tid];
            float o = p[0] + p[32] + p[64] + p[96] + p[128] + p[160] + p[192] + p[224];
            out[off + jh * 32 + tid] = o;
        }
        off = off2;
    }
}

// ---------------- 128x128 MFMA GEMM (m97 structure), N=2048, M=4096 ----------
// C[4096,2048] = ep( A[4096,K](bf16,lda) * Bw[2048,K](bf16)^T )
// global_load_lds width-16 staging, XOR bank swizzle on the global source side.
// EP: 2 xm(bf16) 3 decay(f32) 5 emat1+acc(f32) 6 sigmoid(f32) 7 relu^2(bf16)
//     8 emat1+emat2*acc(f32) 9 plain bf16 10 silu bf16
template <int EP>
__global__ __launch_bounds__(256) void k_gemm128(const u16* __restrict__ A, int lda,
                                                 const u16* __restrict__ Bw,
                                                 void* __restrict__ C, int K,
                                                 const float* __restrict__ evec,
                                                 const float* __restrict__ emat1,
                                                 const float* __restrict__ emat2) {
    __shared__ u16 As[128 * 32];
    __shared__ u16 Bs[128 * 32];
    const int tid = threadIdx.x;
    const int m0 = blockIdx.y << 7, n0 = blockIdx.x << 7;
    const int srow = tid >> 2;                                  // 0..63
    const int scol = (((tid & 3) ^ ((srow >> 1) & 3)) << 3);    // swizzled global chunk
    const int wv = tid >> 6, lane = tid & 63;
    const int wy = (wv >> 1) << 6, wx = (wv & 1) << 6;
    const int lr = lane & 15, lq = lane >> 4;
    const int cofs = ((lq ^ ((lr >> 1) & 3)) << 3);             // swizzled LDS chunk
    f32x4 acc[4][4];
#pragma unroll
    for (int a = 0; a < 4; a++)
#pragma unroll
        for (int bq = 0; bq < 4; bq++) acc[a][bq] = {0.f, 0.f, 0.f, 0.f};
    const u16* gA = A + (size_t)(m0 + srow) * lda + scol;
    const u16* gB = Bw + (size_t)(n0 + srow) * K + scol;
    u16* lA = As + srow * 32 + ((tid & 3) << 3);
    u16* lB = Bs + srow * 32 + ((tid & 3) << 3);
    for (int k0 = 0; k0 < K; k0 += 32) {
        gl_lds16(gA + k0, lA);
        gl_lds16(gA + (size_t)64 * lda + k0, lA + 64 * 32);
        gl_lds16(gB + k0, lB);
        gl_lds16(gB + (size_t)64 * K + k0, lB + 64 * 32);
        __syncthreads();     // drains vmcnt (compiler) -> LDS tiles ready
        bf16x8 af[4], bfr[4];
#pragma unroll
        for (int mt = 0; mt < 4; mt++)
            af[mt] = *reinterpret_cast<const bf16x8*>(As + (wy + mt * 16 + lr) * 32 + cofs);
#pragma unroll
        for (int nt = 0; nt < 4; nt++)
            bfr[nt] = *reinterpret_cast<const bf16x8*>(Bs + (wx + nt * 16 + lr) * 32 + cofs);
#pragma unroll
        for (int mt = 0; mt < 4; mt++)
#pragma unroll
            for (int nt = 0; nt < 4; nt++)
                acc[mt][nt] = __builtin_amdgcn_mfma_f32_16x16x32_bf16(af[mt], bfr[nt], acc[mt][nt], 0, 0, 0);
        __syncthreads();     // protect LDS before next iteration's staging
    }
    const int gmb = m0 + wy + (lq << 2);
    const int gnb = n0 + wx + lr;
#pragma unroll
    for (int mt = 0; mt < 4; mt++) {
#pragma unroll
        for (int nt = 0; nt < 4; nt++) {
            int gn = gnb + nt * 16;
#pragma unroll
            for (int i = 0; i < 4; i++) {
                int gm = gmb + mt * 16 + i;
                size_t idx = (size_t)gm * E + gn;
                float v = acc[mt][nt][i];
                if constexpr (EP == 2) {
                    int l = gm & (LL - 1), bb = gm >> 10;
                    float cur = emat1[idx];
                    float prev = (l > 0) ? emat1[idx - E]
                                         : emat2[(size_t)bb * 66 * E + E + gn];
                    ((u16*)C)[idx] = f2b(cur + (prev - cur) * (evec[gn] + v));
                }
                else if constexpr (EP == 3) ((float*)C)[idx] = expf(-expf(evec[gn] + v));
                else if constexpr (EP == 5) ((float*)C)[idx] = emat1[idx] + v;
                else if constexpr (EP == 6) ((float*)C)[idx] = 1.f / (1.f + expf(-v));
                else if constexpr (EP == 7) { float t = fmaxf(v, 0.f); ((u16*)C)[idx] = f2b(t * t); }
                else if constexpr (EP == 8) ((float*)C)[idx] = emat1[idx] + emat2[idx] * v;
                else if constexpr (EP == 9) ((u16*)C)[idx] = f2b(v);
                else if constexpr (EP == 10) { float sg = 1.f / (1.f + expf(-v)); ((u16*)C)[idx] = f2b(v * sg); }
            }
        }
    }
}

// ---------------- 64-tile GEMM (odd N: 160 / 64), EP1 = tanh bf16 -----------
#define BK  32
#define LDP 40

template <int EP>
__global__ __launch_bounds__(256) void k_gemm(const u16* __restrict__ A, int lda,
                                              const u16* __restrict__ Bw,
                                              void* __restrict__ C,
                                              int M, int N, int K) {
    __shared__ u16 As[64 * LDP];
    __shared__ u16 Bs[64 * LDP];
    const int tid = threadIdx.x;
    const int m0 = blockIdx.y << 6, n0 = blockIdx.x << 6;
    const int srow = tid >> 2, skc = (tid & 3) << 3;
    const int lane = tid & 63, wv = tid >> 6;
    const int wr = (wv >> 1) << 5, wc = (wv & 1) << 5;
    const int lr = lane & 15, lq = lane >> 4;
    f32x4 acc[2][2];
#pragma unroll
    for (int a = 0; a < 2; a++)
#pragma unroll
        for (int bq = 0; bq < 2; bq++) acc[a][bq] = {0.f, 0.f, 0.f, 0.f};
    const u16* aptr = A + (size_t)(m0 + srow) * lda + skc;
    const u16* bptr = Bw + (size_t)(n0 + srow) * K + skc;
    const bool bvalid = (n0 + srow) < N;
    for (int k0 = 0; k0 < K; k0 += BK) {
        float4 av = *reinterpret_cast<const float4*>(aptr + k0);
        float4 bv = bvalid ? *reinterpret_cast<const float4*>(bptr + k0)
                           : make_float4(0.f, 0.f, 0.f, 0.f);
        __syncthreads();
        *reinterpret_cast<float4*>(As + srow * LDP + skc) = av;
        *reinterpret_cast<float4*>(Bs + srow * LDP + skc) = bv;
        __syncthreads();
        bf16x8 a0 = *reinterpret_cast<const bf16x8*>(As + (wr + lr) * LDP + lq * 8);
        bf16x8 a1 = *reinterpret_cast<const bf16x8*>(As + (wr + 16 + lr) * LDP + lq * 8);
        bf16x8 b0 = *reinterpret_cast<const bf16x8*>(Bs + (wc + lr) * LDP + lq * 8);
        bf16x8 b1 = *reinterpret_cast<const bf16x8*>(Bs + (wc + 16 + lr) * LDP + lq * 8);
        acc[0][0] = __builtin_amdgcn_mfma_f32_16x16x32_bf16(a0, b0, acc[0][0], 0, 0, 0);
        acc[0][1] = __builtin_amdgcn_mfma_f32_16x16x32_bf16(a0, b1, acc[0][1], 0, 0, 0);
        acc[1][0] = __builtin_amdgcn_mfma_f32_16x16x32_bf16(a1, b0, acc[1][0], 0, 0, 0);
        acc[1][1] = __builtin_amdgcn_mfma_f32_16x16x32_bf16(a1, b1, acc[1][1], 0, 0, 0);
    }
    const int gmb = m0 + wr + lq * 4;
    const int gnb = n0 + wc + lr;
#pragma unroll
    for (int mi = 0; mi < 2; mi++) {
#pragma unroll
        for (int ni = 0; ni < 2; ni++) {
            int gn = gnb + ni * 16;
            if (gn >= N) continue;
#pragma unroll
            for (int i = 0; i < 4; i++) {
                int gm = gmb + mi * 16 + i;
                size_t idx = (size_t)gm * N + gn;
                float v = acc[mi][ni][i];
                if constexpr (EP == 1) ((u16*)C)[idx] = f2b(tanhf(v));
            }
        }
    }
}

// ---------------- launch ----------------

extern "C" void kernel_launch(void* const* d_in, const int* in_sizes, int n_in,
                              void* d_out, int out_size, void* d_ws, size_t ws_size,
                              hipStream_t stream) {
    const float* x          = (const float*)d_in[0];
    const float* state      = (const float*)d_in[1];
    const float* ln1_w      = (const float*)d_in[2];
    const float* ln1_b      = (const float*)d_in[3];
    const float* ln2_w      = (const float*)d_in[4];
    const float* ln2_b      = (const float*)d_in[5];
    const float* maa_x      = (const float*)d_in[6];
    const float* maa_w1     = (const float*)d_in[7];
    const float* maa_w2     = (const float*)d_in[8];
    const float* maa_stack  = (const float*)d_in[9];
    const float* time_decay = (const float*)d_in[10];
    const float* td_w1      = (const float*)d_in[11];
    const float* td_w2      = (const float*)d_in[12];
    const float* u          = (const float*)d_in[13];
    const float* Wr         = (const float*)d_in[14];
    const float* Wk         = (const float*)d_in[15];
    const float* Wv         = (const float*)d_in[16];
    const float* Wg         = (const float*)d_in[17];
    const float* Wo         = (const float*)d_in[18];
    const float* gn_w       = (const float*)d_in[19];
    const float* gn_b       = (const float*)d_in[20];
    const float* ffn_k      = (const float*)d_in[21];
    const float* ffn_r      = (const float*)d_in[22];
    const float* Wfk        = (const float*)d_in[23];
    const float* Wfr        = (const float*)d_in[24];
    const float* Wfv        = (const float*)d_in[25];

    char* ws = (char*)d_ws;
    float* R0 = (float*)(ws);                        // xa -> wkv -> x1   (32 MiB f32)
    float* R1 = (float*)(ws + 33554432);             // Wdecay -> xc -> rr (32 MiB f32)
    u16*   R2 = (u16*)(ws + 67108864);               // mk/xm slot -> xk2 (16 MiB bf16)
    u16*   R3 = (u16*)(ws + 83886080);               // Rb -> xr2
    u16*   R4 = (u16*)(ws + 100663296);              // Kb -> kk
    u16*   R5 = (u16*)(ws + 117440512);              // Vb
    u16*   R6 = (u16*)(ws + 134217728);              // g -> ogg
    u16*   WB = (u16*)(ws + 150994944);              // weight bf16 slot (8 MiB)
    u16*   Hx = (u16*)(ws + 159383552);              // tanh(mk@w1)  NBL x 160
    u16*   Ht = (u16*)(ws + 160694272);              // tanh(xw@td1) NBL x 64
    u16*  WT1 = (u16*)(ws + 161218560);              // maa_w1^T  160 x 2048
    u16*  WT2 = (u16*)(ws + 161873920);              // maa_w2^T  5 x (2048 x 32)
    u16*  WT3 = (u16*)(ws + 162529280);              // td_w1^T   64 x 2048
    u16*  WT4 = (u16*)(ws + 162791424);              // td_w2^T   2048 x 64

    dim3 blk(256);
    dim3 g128(16, 32);          // N=2048/128, M=4096/128
    dim3 g160(3, 64), g64(1, 64);
    const int ncv = (E * E / 4) / 256;
    const int nel = NBLE / 1024;

    // small-weight transposes (to (N,K) bf16)
    k_transpose<<<(E * 160 + 255) / 256, blk, 0, stream>>>(maa_w1, WT1, E, 160);
    for (int f = 0; f < 5; f++)
        k_transpose<<<(32 * E + 255) / 256, blk, 0, stream>>>(maa_w2 + f * 32 * E, WT2 + f * E * 32, 32, E);
    k_transpose<<<(E * 64 + 255) / 256, blk, 0, stream>>>(td_w1, WT3, E, 64);
    k_transpose<<<(64 * E + 255) / 256, blk, 0, stream>>>(td_w2, WT4, 64, E);

    // time-mix front end
    k_ln<<<NBL, blk, 0, stream>>>(x, ln1_w, ln1_b, R0);                    // xa
    k_mk<<<nel, blk, 0, stream>>>(R0, state, maa_x, R2);                   // mk bf16
    k_gemm<1><<<g160, blk, 0, stream>>>(R2, E, WT1, Hx, NBL, 160, E);

    // decay chain (f=1: w)
    k_gemm128<2><<<g128, blk, 0, stream>>>(Hx + 1 * 32, 160, WT2 + 1 * E * 32, R2, 32,
                                           maa_stack + 1 * E, R0, state);
    k_gemm<1><<<g64, blk, 0, stream>>>(R2, E, WT3, Ht, NBL, 64, E);
    k_gemm128<3><<<g128, blk, 0, stream>>>(Ht, 64, WT4, R1, 64, time_decay, nullptr, nullptr);

    // k projection (f=0)
    k_gemm128<2><<<g128, blk, 0, stream>>>(Hx + 0 * 32, 160, WT2 + 0 * E * 32, R2, 32,
                                           maa_stack + 0 * E, R0, state);
    k_convert<<<ncv, blk, 0, stream>>>(Wk, WB, E * E);
    k_gemm128<9><<<g128, blk, 0, stream>>>(R2, E, WB, R4, E, nullptr, nullptr, nullptr);

    // v projection (f=2)
    k_gemm128<2><<<g128, blk, 0, stream>>>(Hx + 2 * 32, 160, WT2 + 2 * E * 32, R2, 32,
                                           maa_stack + 2 * E, R0, state);
    k_convert<<<ncv, blk, 0, stream>>>(Wv, WB, E * E);
    k_gemm128<9><<<g128, blk, 0, stream>>>(R2, E, WB, R5, E, nullptr, nullptr, nullptr);

    // g projection (f=4)
    k_gemm128<2><<<g128, blk, 0, stream>>>(Hx + 4 * 32, 160, WT2 + 4 * E * 32, R2, 32,
                                           maa_stack + 4 * E, R0, state);
    k_convert<<<ncv, blk, 0, stream>>>(Wg, WB, E * E);
    k_gemm128<10><<<g128, blk, 0, stream>>>(R2, E, WB, R6, E, nullptr, nullptr, nullptr);

    // r projection (f=3) — last use of xa (R0)
    k_gemm128<2><<<g128, blk, 0, stream>>>(Hx + 3 * 32, 160, WT2 + 3 * E * 32, R2, 32,
                                           maa_stack + 3 * E, R0, state);
    k_convert<<<ncv, blk, 0, stream>>>(Wr, WB, E * E);
    k_gemm128<9><<<g128, blk, 0, stream>>>(R2, E, WB, R3, E, nullptr, nullptr, nullptr);

    // sequential WKV scan -> R0 (wkv f32), then groupnorm * g -> ogg (R6 in place)
    k_scan<<<256, blk, 0, stream>>>(R3, R4, R5, R1, state, u, R0);
    k_gnorm<<<NBL * HHH / 4, blk, 0, stream>>>(R0, R6, gn_w, gn_b, R6);

    // output projection + residual -> x1 (R0; wkv dead)
    k_convert<<<ncv, blk, 0, stream>>>(Wo, WB, E * E);
    k_gemm128<5><<<g128, blk, 0, stream>>>(R6, E, WB, R0, E, nullptr, x, nullptr);

    // channel mix
    k_ln<<<NBL, blk, 0, stream>>>(R0, ln2_w, ln2_b, R1);                   // xc
    k_mix2<<<nel, blk, 0, stream>>>(R1, state, ffn_k, ffn_r, R2, R3);      // xk2, xr2
    k_convert<<<ncv, blk, 0, stream>>>(Wfk, WB, E * E);
    k_gemm128<7><<<g128, blk, 0, stream>>>(R2, E, WB, R4, E, nullptr, nullptr, nullptr);
    k_convert<<<ncv, blk, 0, stream>>>(Wfr, WB, E * E);
    k_gemm128<6><<<g128, blk, 0, stream>>>(R3, E, WB, R1, E, nullptr, nullptr, nullptr);
    k_convert<<<ncv, blk, 0, stream>>>(Wfv, WB, E * E);
    k_gemm128<8><<<g128, blk, 0, stream>>>(R4, E, WB, (float*)d_out, E, nullptr, R0, R1);
}

// Round 4
// 1251.366 us; speedup vs baseline: 1.4936x; 1.0100x over previous
//
#include <hip/hip_runtime.h>

// RWKV-6 style block on MI355X (gfx950).
// E=2048, H=32, S=64, L=1024, B=4.
// Round 4: barrier-free intra-wave WKV scan (shuffle reduction, prefetch x2).

#define E     2048
#define LL    1024
#define HHH   32
#define SSS   64
#define NBL   4096      // B*L
#define NBLE  8388608   // B*L*E

typedef short bf16x8 __attribute__((ext_vector_type(8)));
typedef float f32x4  __attribute__((ext_vector_type(4)));
using u16 = unsigned short;

__device__ __forceinline__ u16 f2b(float f) {
    union { float f; unsigned int u; } c; c.f = f;
    unsigned int u = c.u;
    unsigned int r = (u + 0x7fffu + ((u >> 16) & 1u)) >> 16;
    return (u16)r;
}
__device__ __forceinline__ float b2f(u16 b) {
    union { unsigned int u; float f; } c; c.u = ((unsigned int)b) << 16; return c.f;
}

__device__ __forceinline__ float wave_sum(float v) {
#pragma unroll
    for (int m = 32; m >= 1; m >>= 1) v += __shfl_xor(v, m, 64);
    return v;
}

__device__ __forceinline__ void gl_lds16(const u16* g, u16* l) {
    __builtin_amdgcn_global_load_lds((const __attribute__((address_space(1))) unsigned int*)g,
                                     (__attribute__((address_space(3))) unsigned int*)l, 16, 0, 0);
}

// ---------------- elementwise / prep kernels ----------------

__global__ __launch_bounds__(256) void k_convert(const float* __restrict__ in,
                                                 u16* __restrict__ out, int n) {
    int i = (blockIdx.x * 256 + threadIdx.x) * 4;
    if (i >= n) return;
    float4 v = *reinterpret_cast<const float4*>(in + i);
    ushort4 o = make_ushort4(f2b(v.x), f2b(v.y), f2b(v.z), f2b(v.w));
    *reinterpret_cast<ushort4*>(out + i) = o;
}

// in (R,C) fp32 -> out (C,R) bf16
__global__ __launch_bounds__(256) void k_transpose(const float* __restrict__ in,
                                                   u16* __restrict__ out, int R, int C) {
    int i = blockIdx.x * 256 + threadIdx.x;
    if (i >= R * C) return;
    int r = i / C, c = i - r * C;
    out[c * R + r] = f2b(in[i]);
}

__global__ __launch_bounds__(256) void k_ln(const float* __restrict__ x,
                                            const float* __restrict__ w,
                                            const float* __restrict__ b,
                                            float* __restrict__ out) {
    int row = blockIdx.x, tid = threadIdx.x;
    const float* xr = x + (size_t)row * E + tid * 8;
    float4 v0 = *reinterpret_cast<const float4*>(xr);
    float4 v1 = *reinterpret_cast<const float4*>(xr + 4);
    float s = v0.x + v0.y + v0.z + v0.w + v1.x + v1.y + v1.z + v1.w;
    __shared__ float red[4];
    s = wave_sum(s);
    int wid = tid >> 6, lane = tid & 63;
    if (lane == 0) red[wid] = s;
    __syncthreads();
    float mean = (red[0] + red[1] + red[2] + red[3]) * (1.0f / E);
    __syncthreads();
    float q = 0.f;
    q += (v0.x - mean) * (v0.x - mean); q += (v0.y - mean) * (v0.y - mean);
    q += (v0.z - mean) * (v0.z - mean); q += (v0.w - mean) * (v0.w - mean);
    q += (v1.x - mean) * (v1.x - mean); q += (v1.y - mean) * (v1.y - mean);
    q += (v1.z - mean) * (v1.z - mean); q += (v1.w - mean) * (v1.w - mean);
    q = wave_sum(q);
    if (lane == 0) red[wid] = q;
    __syncthreads();
    float inv = rsqrtf((red[0] + red[1] + red[2] + red[3]) * (1.0f / E) + 1e-5f);
    int e = tid * 8;
    float4 w0 = *reinterpret_cast<const float4*>(w + e);
    float4 w1 = *reinterpret_cast<const float4*>(w + e + 4);
    float4 b0 = *reinterpret_cast<const float4*>(b + e);
    float4 b1 = *reinterpret_cast<const float4*>(b + e + 4);
    float4 o0, o1;
    o0.x = (v0.x - mean) * inv * w0.x + b0.x; o0.y = (v0.y - mean) * inv * w0.y + b0.y;
    o0.z = (v0.z - mean) * inv * w0.z + b0.z; o0.w = (v0.w - mean) * inv * w0.w + b0.w;
    o1.x = (v1.x - mean) * inv * w1.x + b1.x; o1.y = (v1.y - mean) * inv * w1.y + b1.y;
    o1.z = (v1.z - mean) * inv * w1.z + b1.z; o1.w = (v1.w - mean) * inv * w1.w + b1.w;
    float* op = out + (size_t)row * E + e;
    *reinterpret_cast<float4*>(op) = o0;
    *reinterpret_cast<float4*>(op + 4) = o1;
}

// mk = bf16(xa + sx*maa_x), sx recomputed inline (time-mix shift, state row 1)
__global__ __launch_bounds__(256) void k_mk(const float* __restrict__ xa,
                                            const float* __restrict__ state,
                                            const float* __restrict__ maa_x,
                                            u16* __restrict__ out) {
    int i = (blockIdx.x * 256 + threadIdx.x) * 4;
    if (i >= NBLE) return;
    int n = i >> 11, e = i & (E - 1);
    int l = n & (LL - 1), b = n >> 10;
    float4 cur = *reinterpret_cast<const float4*>(xa + i);
    float4 prev;
    if (l > 0) prev = *reinterpret_cast<const float4*>(xa + i - E);
    else       prev = *reinterpret_cast<const float4*>(state + (size_t)b * 66 * E + E + e);
    float4 m = *reinterpret_cast<const float4*>(maa_x + e);
    ushort4 o = make_ushort4(f2b(cur.x + (prev.x - cur.x) * m.x),
                             f2b(cur.y + (prev.y - cur.y) * m.y),
                             f2b(cur.z + (prev.z - cur.z) * m.z),
                             f2b(cur.w + (prev.w - cur.w) * m.w));
    *reinterpret_cast<ushort4*>(out + i) = o;
}

// channel-mix token shift (state row 0) + two mixes -> bf16
__global__ __launch_bounds__(256) void k_mix2(const float* __restrict__ xc,
                                              const float* __restrict__ state,
                                              const float* __restrict__ mk,
                                              const float* __restrict__ mr,
                                              u16* __restrict__ xk2,
                                              u16* __restrict__ xr2) {
    int i = (blockIdx.x * 256 + threadIdx.x) * 4;
    if (i >= NBLE) return;
    int n = i >> 11, e = i & (E - 1);
    int l = n & (LL - 1), b = n >> 10;
    float4 cur = *reinterpret_cast<const float4*>(xc + i);
    float4 prev;
    if (l > 0) prev = *reinterpret_cast<const float4*>(xc + i - E);
    else       prev = *reinterpret_cast<const float4*>(state + (size_t)b * 66 * E + e);
    float4 sx = make_float4(prev.x - cur.x, prev.y - cur.y, prev.z - cur.z, prev.w - cur.w);
    float4 k4 = *reinterpret_cast<const float4*>(mk + e);
    float4 r4 = *reinterpret_cast<const float4*>(mr + e);
    ushort4 ok = make_ushort4(f2b(cur.x + sx.x * k4.x), f2b(cur.y + sx.y * k4.y),
                              f2b(cur.z + sx.z * k4.z), f2b(cur.w + sx.w * k4.w));
    ushort4 orr = make_ushort4(f2b(cur.x + sx.x * r4.x), f2b(cur.y + sx.y * r4.y),
                               f2b(cur.z + sx.z * r4.z), f2b(cur.w + sx.w * r4.w));
    *reinterpret_cast<ushort4*>(xk2 + i) = ok;
    *reinterpret_cast<ushort4*>(xr2 + i) = orr;
}

// per-head groupnorm over S=64, *gn_w+gn_b, *g (bf16, in-place ok) -> bf16
__global__ __launch_bounds__(256) void k_gnorm(const float* __restrict__ wkv,
                                               const u16* __restrict__ g,
                                               const float* __restrict__ gw,
                                               const float* __restrict__ gb,
                                               u16* __restrict__ ogg) {
    int gidx = blockIdx.x * 4 + (threadIdx.x >> 6);
    int lane = threadIdx.x & 63;
    int n = gidx >> 5, h = gidx & 31;
    size_t base = (size_t)n * E + h * SSS;
    float v = wkv[base + lane];
    float mean = wave_sum(v) * (1.0f / SSS);
    float d = v - mean;
    float var = wave_sum(d * d) * (1.0f / SSS);
    float norm = d * rsqrtf(var + 1e-5f);
    int e = h * SSS + lane;
    float res = norm * gw[e] + gb[e];
    float gv = b2f(g[base + lane]);
    ogg[base + lane] = f2b(res * gv);
}

// ---------------- WKV sequential scan (barrier-free, intra-wave) ----------
// grid = B*H*2 = 256 blocks of 256 (4 waves).  Wave handles 8 j-columns x
// full i range: lane = ig*8 + jl, lane owns 8 state rows.  Reduction over
// ig via 3 shfl_xor.  r,k,v bf16; w,state,acc fp32.  Prefetch distance 2.
struct PF {
    ushort4 r0, r1, k0, k1;
    float4 w0, w1;
    u16 v;
};

__device__ __forceinline__ PF pf_load(const u16* __restrict__ Rb,
                                      const u16* __restrict__ Kb,
                                      const u16* __restrict__ Vb,
                                      const float* __restrict__ W,
                                      size_t off, int i0, int j) {
    PF p;
    p.r0 = *reinterpret_cast<const ushort4*>(Rb + off + i0);
    p.r1 = *reinterpret_cast<const ushort4*>(Rb + off + i0 + 4);
    p.k0 = *reinterpret_cast<const ushort4*>(Kb + off + i0);
    p.k1 = *reinterpret_cast<const ushort4*>(Kb + off + i0 + 4);
    p.w0 = *reinterpret_cast<const float4*>(W + off + i0);
    p.w1 = *reinterpret_cast<const float4*>(W + off + i0 + 4);
    p.v  = Vb[off + j];
    return p;
}

__device__ __forceinline__ float step8(const PF& c, float* s, const float* uu) {
    float vj = b2f(c.v);
    float acc = 0.f, a;
    a = b2f(c.k0.x) * vj; acc += b2f(c.r0.x) * fmaf(uu[0], a, s[0]); s[0] = fmaf(c.w0.x, s[0], a);
    a = b2f(c.k0.y) * vj; acc += b2f(c.r0.y) * fmaf(uu[1], a, s[1]); s[1] = fmaf(c.w0.y, s[1], a);
    a = b2f(c.k0.z) * vj; acc += b2f(c.r0.z) * fmaf(uu[2], a, s[2]); s[2] = fmaf(c.w0.z, s[2], a);
    a = b2f(c.k0.w) * vj; acc += b2f(c.r0.w) * fmaf(uu[3], a, s[3]); s[3] = fmaf(c.w0.w, s[3], a);
    a = b2f(c.k1.x) * vj; acc += b2f(c.r1.x) * fmaf(uu[4], a, s[4]); s[4] = fmaf(c.w1.x, s[4], a);
    a = b2f(c.k1.y) * vj; acc += b2f(c.r1.y) * fmaf(uu[5], a, s[5]); s[5] = fmaf(c.w1.y, s[5], a);
    a = b2f(c.k1.z) * vj; acc += b2f(c.r1.z) * fmaf(uu[6], a, s[6]); s[6] = fmaf(c.w1.z, s[6], a);
    a = b2f(c.k1.w) * vj; acc += b2f(c.r1.w) * fmaf(uu[7], a, s[7]); s[7] = fmaf(c.w1.w, s[7], a);
    return acc;
}

__global__ __launch_bounds__(256) void k_scan(const u16* __restrict__ Rb,
                                              const u16* __restrict__ Kb,
                                              const u16* __restrict__ Vb,
                                              const float* __restrict__ W,
                                              const float* __restrict__ state,
                                              const float* __restrict__ u,
                                              float* __restrict__ out) {
    int blk = blockIdx.x;
    int b = blk >> 6;
    int rem = blk & 63;
    int h = rem >> 1, jh = rem & 1;
    int tid = threadIdx.x;
    int wvid = tid >> 6;            // 0..3 -> j octet within half
    int lane = tid & 63;
    int ig = lane >> 3, jl = lane & 7;
    int j = jh * 32 + wvid * 8 + jl;
    int i0 = ig * 8;
    float s[8], uu[8];
    const float* s0 = state + (size_t)b * 66 * E + 2 * E + h * (SSS * SSS);
#pragma unroll
    for (int ii = 0; ii < 8; ii++) {
        s[ii] = s0[(i0 + ii) * SSS + j];
        uu[ii] = u[h * SSS + i0 + ii];
    }
    size_t off = (size_t)b * LL * E + h * SSS;
    float* op = out + off + j;
    PF p0 = pf_load(Rb, Kb, Vb, W, off, i0, j);
    PF p1 = pf_load(Rb, Kb, Vb, W, off + E, i0, j);
    for (int t = 0; t < LL; t += 2) {
        PF c0 = p0;
        // prefetch t+2 (tail reads <8KB past logical end, still inside ws)
        p0 = pf_load(Rb, Kb, Vb, W, off + 2 * E, i0, j);
        float acc = step8(c0, s, uu);
        acc += __shfl_xor(acc, 8, 64);
        acc += __shfl_xor(acc, 16, 64);
        acc += __shfl_xor(acc, 32, 64);
        if (ig == 0) op[0] = acc;
        PF c1 = p1;
        p1 = pf_load(Rb, Kb, Vb, W, off + 3 * E, i0, j);
        float acc1 = step8(c1, s, uu);
        acc1 += __shfl_xor(acc1, 8, 64);
        acc1 += __shfl_xor(acc1, 16, 64);
        acc1 += __shfl_xor(acc1, 32, 64);
        if (ig == 0) op[E] = acc1;
        off += 2 * E;
        op += 2 * E;
    }
}

// ---------------- 128x128 MFMA GEMM (m97 structure), N=2048, M=4096 ----------
// C[4096,2048] = ep( A[4096,K](bf16,lda) * Bw[2048,K](bf16)^T )
// global_load_lds width-16 staging, XOR bank swizzle on the global source side.
// EP: 2 xm(bf16) 3 decay(f32) 5 emat1+acc(f32) 6 sigmoid(f32) 7 relu^2(bf16)
//     8 emat1+emat2*acc(f32) 9 plain bf16 10 silu bf16
template <int EP>
__global__ __launch_bounds__(256) void k_gemm128(const u16* __restrict__ A, int lda,
                                                 const u16* __restrict__ Bw,
                                                 void* __restrict__ C, int K,
                                                 const float* __restrict__ evec,
                                                 const float* __restrict__ emat1,
                                                 const float* __restrict__ emat2) {
    __shared__ u16 As[128 * 32];
    __shared__ u16 Bs[128 * 32];
    const int tid = threadIdx.x;
    const int m0 = blockIdx.y << 7, n0 = blockIdx.x << 7;
    const int srow = tid >> 2;                                  // 0..63
    const int scol = (((tid & 3) ^ ((srow >> 1) & 3)) << 3);    // swizzled global chunk
    const int wv = tid >> 6, lane = tid & 63;
    const int wy = (wv >> 1) << 6, wx = (wv & 1) << 6;
    const int lr = lane & 15, lq = lane >> 4;
    const int cofs = ((lq ^ ((lr >> 1) & 3)) << 3);             // swizzled LDS chunk
    f32x4 acc[4][4];
#pragma unroll
    for (int a = 0; a < 4; a++)
#pragma unroll
        for (int bq = 0; bq < 4; bq++) acc[a][bq] = {0.f, 0.f, 0.f, 0.f};
    const u16* gA = A + (size_t)(m0 + srow) * lda + scol;
    const u16* gB = Bw + (size_t)(n0 + srow) * K + scol;
    u16* lA = As + srow * 32 + ((tid & 3) << 3);
    u16* lB = Bs + srow * 32 + ((tid & 3) << 3);
    for (int k0 = 0; k0 < K; k0 += 32) {
        gl_lds16(gA + k0, lA);
        gl_lds16(gA + (size_t)64 * lda + k0, lA + 64 * 32);
        gl_lds16(gB + k0, lB);
        gl_lds16(gB + (size_t)64 * K + k0, lB + 64 * 32);
        __syncthreads();     // drains vmcnt (compiler) -> LDS tiles ready
        bf16x8 af[4], bfr[4];
#pragma unroll
        for (int mt = 0; mt < 4; mt++)
            af[mt] = *reinterpret_cast<const bf16x8*>(As + (wy + mt * 16 + lr) * 32 + cofs);
#pragma unroll
        for (int nt = 0; nt < 4; nt++)
            bfr[nt] = *reinterpret_cast<const bf16x8*>(Bs + (wx + nt * 16 + lr) * 32 + cofs);
#pragma unroll
        for (int mt = 0; mt < 4; mt++)
#pragma unroll
            for (int nt = 0; nt < 4; nt++)
                acc[mt][nt] = __builtin_amdgcn_mfma_f32_16x16x32_bf16(af[mt], bfr[nt], acc[mt][nt], 0, 0, 0);
        __syncthreads();     // protect LDS before next iteration's staging
    }
    const int gmb = m0 + wy + (lq << 2);
    const int gnb = n0 + wx + lr;
#pragma unroll
    for (int mt = 0; mt < 4; mt++) {
#pragma unroll
        for (int nt = 0; nt < 4; nt++) {
            int gn = gnb + nt * 16;
#pragma unroll
            for (int i = 0; i < 4; i++) {
                int gm = gmb + mt * 16 + i;
                size_t idx = (size_t)gm * E + gn;
                float v = acc[mt][nt][i];
                if constexpr (EP == 2) {
                    int l = gm & (LL - 1), bb = gm >> 10;
                    float cur = emat1[idx];
                    float prev = (l > 0) ? emat1[idx - E]
                                         : emat2[(size_t)bb * 66 * E + E + gn];
                    ((u16*)C)[idx] = f2b(cur + (prev - cur) * (evec[gn] + v));
                }
                else if constexpr (EP == 3) ((float*)C)[idx] = expf(-expf(evec[gn] + v));
                else if constexpr (EP == 5) ((float*)C)[idx] = emat1[idx] + v;
                else if constexpr (EP == 6) ((float*)C)[idx] = 1.f / (1.f + expf(-v));
                else if constexpr (EP == 7) { float t = fmaxf(v, 0.f); ((u16*)C)[idx] = f2b(t * t); }
                else if constexpr (EP == 8) ((float*)C)[idx] = emat1[idx] + emat2[idx] * v;
                else if constexpr (EP == 9) ((u16*)C)[idx] = f2b(v);
                else if constexpr (EP == 10) { float sg = 1.f / (1.f + expf(-v)); ((u16*)C)[idx] = f2b(v * sg); }
            }
        }
    }
}

// ---------------- 64-tile GEMM (odd N: 160 / 64), EP1 = tanh bf16 -----------
#define BK  32
#define LDP 40

template <int EP>
__global__ __launch_bounds__(256) void k_gemm(const u16* __restrict__ A, int lda,
                                              const u16* __restrict__ Bw,
                                              void* __restrict__ C,
                                              int M, int N, int K) {
    __shared__ u16 As[64 * LDP];
    __shared__ u16 Bs[64 * LDP];
    const int tid = threadIdx.x;
    const int m0 = blockIdx.y << 6, n0 = blockIdx.x << 6;
    const int srow = tid >> 2, skc = (tid & 3) << 3;
    const int lane = tid & 63, wv = tid >> 6;
    const int wr = (wv >> 1) << 5, wc = (wv & 1) << 5;
    const int lr = lane & 15, lq = lane >> 4;
    f32x4 acc[2][2];
#pragma unroll
    for (int a = 0; a < 2; a++)
#pragma unroll
        for (int bq = 0; bq < 2; bq++) acc[a][bq] = {0.f, 0.f, 0.f, 0.f};
    const u16* aptr = A + (size_t)(m0 + srow) * lda + skc;
    const u16* bptr = Bw + (size_t)(n0 + srow) * K + skc;
    const bool bvalid = (n0 + srow) < N;
    for (int k0 = 0; k0 < K; k0 += BK) {
        float4 av = *reinterpret_cast<const float4*>(aptr + k0);
        float4 bv = bvalid ? *reinterpret_cast<const float4*>(bptr + k0)
                           : make_float4(0.f, 0.f, 0.f, 0.f);
        __syncthreads();
        *reinterpret_cast<float4*>(As + srow * LDP + skc) = av;
        *reinterpret_cast<float4*>(Bs + srow * LDP + skc) = bv;
        __syncthreads();
        bf16x8 a0 = *reinterpret_cast<const bf16x8*>(As + (wr + lr) * LDP + lq * 8);
        bf16x8 a1 = *reinterpret_cast<const bf16x8*>(As + (wr + 16 + lr) * LDP + lq * 8);
        bf16x8 b0 = *reinterpret_cast<const bf16x8*>(Bs + (wc + lr) * LDP + lq * 8);
        bf16x8 b1 = *reinterpret_cast<const bf16x8*>(Bs + (wc + 16 + lr) * LDP + lq * 8);
        acc[0][0] = __builtin_amdgcn_mfma_f32_16x16x32_bf16(a0, b0, acc[0][0], 0, 0, 0);
        acc[0][1] = __builtin_amdgcn_mfma_f32_16x16x32_bf16(a0, b1, acc[0][1], 0, 0, 0);
        acc[1][0] = __builtin_amdgcn_mfma_f32_16x16x32_bf16(a1, b0, acc[1][0], 0, 0, 0);
        acc[1][1] = __builtin_amdgcn_mfma_f32_16x16x32_bf16(a1, b1, acc[1][1], 0, 0, 0);
    }
    const int gmb = m0 + wr + lq * 4;
    const int gnb = n0 + wc + lr;
#pragma unroll
    for (int mi = 0; mi < 2; mi++) {
#pragma unroll
        for (int ni = 0; ni < 2; ni++) {
            int gn = gnb + ni * 16;
            if (gn >= N) continue;
#pragma unroll
            for (int i = 0; i < 4; i++) {
                int gm = gmb + mi * 16 + i;
                size_t idx = (size_t)gm * N + gn;
                float v = acc[mi][ni][i];
                if constexpr (EP == 1) ((u16*)C)[idx] = f2b(tanhf(v));
            }
        }
    }
}

// ---------------- launch ----------------

extern "C" void kernel_launch(void* const* d_in, const int* in_sizes, int n_in,
                              void* d_out, int out_size, void* d_ws, size_t ws_size,
                              hipStream_t stream) {
    const float* x          = (const float*)d_in[0];
    const float* state      = (const float*)d_in[1];
    const float* ln1_w      = (const float*)d_in[2];
    const float* ln1_b      = (const float*)d_in[3];
    const float* ln2_w      = (const float*)d_in[4];
    const float* ln2_b      = (const float*)d_in[5];
    const float* maa_x      = (const float*)d_in[6];
    const float* maa_w1     = (const float*)d_in[7];
    const float* maa_w2     = (const float*)d_in[8];
    const float* maa_stack  = (const float*)d_in[9];
    const float* time_decay = (const float*)d_in[10];
    const float* td_w1      = (const float*)d_in[11];
    const float* td_w2      = (const float*)d_in[12];
    const float* u          = (const float*)d_in[13];
    const float* Wr         = (const float*)d_in[14];
    const float* Wk         = (const float*)d_in[15];
    const float* Wv         = (const float*)d_in[16];
    const float* Wg         = (const float*)d_in[17];
    const float* Wo         = (const float*)d_in[18];
    const float* gn_w       = (const float*)d_in[19];
    const float* gn_b       = (const float*)d_in[20];
    const float* ffn_k      = (const float*)d_in[21];
    const float* ffn_r      = (const float*)d_in[22];
    const float* Wfk        = (const float*)d_in[23];
    const float* Wfr        = (const float*)d_in[24];
    const float* Wfv        = (const float*)d_in[25];

    char* ws = (char*)d_ws;
    float* R0 = (float*)(ws);                        // xa -> wkv -> x1   (32 MiB f32)
    float* R1 = (float*)(ws + 33554432);             // Wdecay -> xc -> rr (32 MiB f32)
    u16*   R2 = (u16*)(ws + 67108864);               // mk/xm slot -> xk2 (16 MiB bf16)
    u16*   R3 = (u16*)(ws + 83886080);               // Rb -> xr2
    u16*   R4 = (u16*)(ws + 100663296);              // Kb -> kk
    u16*   R5 = (u16*)(ws + 117440512);              // Vb
    u16*   R6 = (u16*)(ws + 134217728);              // g -> ogg
    u16*   WB = (u16*)(ws + 150994944);              // weight bf16 slot (8 MiB)
    u16*   Hx = (u16*)(ws + 159383552);              // tanh(mk@w1)  NBL x 160
    u16*   Ht = (u16*)(ws + 160694272);              // tanh(xw@td1) NBL x 64
    u16*  WT1 = (u16*)(ws + 161218560);              // maa_w1^T  160 x 2048
    u16*  WT2 = (u16*)(ws + 161873920);              // maa_w2^T  5 x (2048 x 32)
    u16*  WT3 = (u16*)(ws + 162529280);              // td_w1^T   64 x 2048
    u16*  WT4 = (u16*)(ws + 162791424);              // td_w2^T   2048 x 64

    dim3 blk(256);
    dim3 g128(16, 32);          // N=2048/128, M=4096/128
    dim3 g160(3, 64), g64(1, 64);
    const int ncv = (E * E / 4) / 256;
    const int nel = NBLE / 1024;

    // small-weight transposes (to (N,K) bf16)
    k_transpose<<<(E * 160 + 255) / 256, blk, 0, stream>>>(maa_w1, WT1, E, 160);
    for (int f = 0; f < 5; f++)
        k_transpose<<<(32 * E + 255) / 256, blk, 0, stream>>>(maa_w2 + f * 32 * E, WT2 + f * E * 32, 32, E);
    k_transpose<<<(E * 64 + 255) / 256, blk, 0, stream>>>(td_w1, WT3, E, 64);
    k_transpose<<<(64 * E + 255) / 256, blk, 0, stream>>>(td_w2, WT4, 64, E);

    // time-mix front end
    k_ln<<<NBL, blk, 0, stream>>>(x, ln1_w, ln1_b, R0);                    // xa
    k_mk<<<nel, blk, 0, stream>>>(R0, state, maa_x, R2);                   // mk bf16
    k_gemm<1><<<g160, blk, 0, stream>>>(R2, E, WT1, Hx, NBL, 160, E);

    // decay chain (f=1: w)
    k_gemm128<2><<<g128, blk, 0, stream>>>(Hx + 1 * 32, 160, WT2 + 1 * E * 32, R2, 32,
                                           maa_stack + 1 * E, R0, state);
    k_gemm<1><<<g64, blk, 0, stream>>>(R2, E, WT3, Ht, NBL, 64, E);
    k_gemm128<3><<<g128, blk, 0, stream>>>(Ht, 64, WT4, R1, 64, time_decay, nullptr, nullptr);

    // k projection (f=0)
    k_gemm128<2><<<g128, blk, 0, stream>>>(Hx + 0 * 32, 160, WT2 + 0 * E * 32, R2, 32,
                                           maa_stack + 0 * E, R0, state);
    k_convert<<<ncv, blk, 0, stream>>>(Wk, WB, E * E);
    k_gemm128<9><<<g128, blk, 0, stream>>>(R2, E, WB, R4, E, nullptr, nullptr, nullptr);

    // v projection (f=2)
    k_gemm128<2><<<g128, blk, 0, stream>>>(Hx + 2 * 32, 160, WT2 + 2 * E * 32, R2, 32,
                                           maa_stack + 2 * E, R0, state);
    k_convert<<<ncv, blk, 0, stream>>>(Wv, WB, E * E);
    k_gemm128<9><<<g128, blk, 0, stream>>>(R2, E, WB, R5, E, nullptr, nullptr, nullptr);

    // g projection (f=4)
    k_gemm128<2><<<g128, blk, 0, stream>>>(Hx + 4 * 32, 160, WT2 + 4 * E * 32, R2, 32,
                                           maa_stack + 4 * E, R0, state);
    k_convert<<<ncv, blk, 0, stream>>>(Wg, WB, E * E);
    k_gemm128<10><<<g128, blk, 0, stream>>>(R2, E, WB, R6, E, nullptr, nullptr, nullptr);

    // r projection (f=3) — last use of xa (R0)
    k_gemm128<2><<<g128, blk, 0, stream>>>(Hx + 3 * 32, 160, WT2 + 3 * E * 32, R2, 32,
                                           maa_stack + 3 * E, R0, state);
    k_convert<<<ncv, blk, 0, stream>>>(Wr, WB, E * E);
    k_gemm128<9><<<g128, blk, 0, stream>>>(R2, E, WB, R3, E, nullptr, nullptr, nullptr);

    // sequential WKV scan -> R0 (wkv f32), then groupnorm * g -> ogg (R6 in place)
    k_scan<<<256, blk, 0, stream>>>(R3, R4, R5, R1, state, u, R0);
    k_gnorm<<<NBL * HHH / 4, blk, 0, stream>>>(R0, R6, gn_w, gn_b, R6);

    // output projection + residual -> x1 (R0; wkv dead)
    k_convert<<<ncv, blk, 0, stream>>>(Wo, WB, E * E);
    k_gemm128<5><<<g128, blk, 0, stream>>>(R6, E, WB, R0, E, nullptr, x, nullptr);

    // channel mix
    k_ln<<<NBL, blk, 0, stream>>>(R0, ln2_w, ln2_b, R1);                   // xc
    k_mix2<<<nel, blk, 0, stream>>>(R1, state, ffn_k, ffn_r, R2, R3);      // xk2, xr2
    k_convert<<<ncv, blk, 0, stream>>>(Wfk, WB, E * E);
    k_gemm128<7><<<g128, blk, 0, stream>>>(R2, E, WB, R4, E, nullptr, nullptr, nullptr);
    k_convert<<<ncv, blk, 0, stream>>>(Wfr, WB, E * E);
    k_gemm128<6><<<g128, blk, 0, stream>>>(R3, E, WB, R1, E, nullptr, nullptr, nullptr);
    k_convert<<<ncv, blk, 0, stream>>>(Wfv, WB, E * E);
    k_gemm128<8><<<g128, blk, 0, stream>>>(R4, E, WB, (float*)d_out, E, nullptr, R0, R1);
}

// Round 5
// 1154.477 us; speedup vs baseline: 1.6190x; 1.0839x over previous
//
#include <hip/hip_runtime.h>

// RWKV-6 style block on MI355X (gfx950).
// E=2048, H=32, S=64, L=1024, B=4.
// Round 5: WKV scan via chunked LDS pipeline (global_load_lds, double buffer,
//          1 barrier / 16 steps) at 2 waves/SIMD.

#define E     2048
#define LL    1024
#define HHH   32
#define SSS   64
#define NBL   4096      // B*L
#define NBLE  8388608   // B*L*E

typedef short bf16x8 __attribute__((ext_vector_type(8)));
typedef float f32x4  __attribute__((ext_vector_type(4)));
using u16 = unsigned short;

__device__ __forceinline__ u16 f2b(float f) {
    union { float f; unsigned int u; } c; c.f = f;
    unsigned int u = c.u;
    unsigned int r = (u + 0x7fffu + ((u >> 16) & 1u)) >> 16;
    return (u16)r;
}
__device__ __forceinline__ float b2f(u16 b) {
    union { unsigned int u; float f; } c; c.u = ((unsigned int)b) << 16; return c.f;
}

__device__ __forceinline__ float wave_sum(float v) {
#pragma unroll
    for (int m = 32; m >= 1; m >>= 1) v += __shfl_xor(v, m, 64);
    return v;
}

__device__ __forceinline__ void gl_lds16(const void* g, void* l) {
    __builtin_amdgcn_global_load_lds((const __attribute__((address_space(1))) unsigned int*)g,
                                     (__attribute__((address_space(3))) unsigned int*)l, 16, 0, 0);
}

// ---------------- elementwise / prep kernels ----------------

__global__ __launch_bounds__(256) void k_convert(const float* __restrict__ in,
                                                 u16* __restrict__ out, int n) {
    int i = (blockIdx.x * 256 + threadIdx.x) * 4;
    if (i >= n) return;
    float4 v = *reinterpret_cast<const float4*>(in + i);
    ushort4 o = make_ushort4(f2b(v.x), f2b(v.y), f2b(v.z), f2b(v.w));
    *reinterpret_cast<ushort4*>(out + i) = o;
}

// in (R,C) fp32 -> out (C,R) bf16
__global__ __launch_bounds__(256) void k_transpose(const float* __restrict__ in,
                                                   u16* __restrict__ out, int R, int C) {
    int i = blockIdx.x * 256 + threadIdx.x;
    if (i >= R * C) return;
    int r = i / C, c = i - r * C;
    out[c * R + r] = f2b(in[i]);
}

__global__ __launch_bounds__(256) void k_ln(const float* __restrict__ x,
                                            const float* __restrict__ w,
                                            const float* __restrict__ b,
                                            float* __restrict__ out) {
    int row = blockIdx.x, tid = threadIdx.x;
    const float* xr = x + (size_t)row * E + tid * 8;
    float4 v0 = *reinterpret_cast<const float4*>(xr);
    float4 v1 = *reinterpret_cast<const float4*>(xr + 4);
    float s = v0.x + v0.y + v0.z + v0.w + v1.x + v1.y + v1.z + v1.w;
    __shared__ float red[4];
    s = wave_sum(s);
    int wid = tid >> 6, lane = tid & 63;
    if (lane == 0) red[wid] = s;
    __syncthreads();
    float mean = (red[0] + red[1] + red[2] + red[3]) * (1.0f / E);
    __syncthreads();
    float q = 0.f;
    q += (v0.x - mean) * (v0.x - mean); q += (v0.y - mean) * (v0.y - mean);
    q += (v0.z - mean) * (v0.z - mean); q += (v0.w - mean) * (v0.w - mean);
    q += (v1.x - mean) * (v1.x - mean); q += (v1.y - mean) * (v1.y - mean);
    q += (v1.z - mean) * (v1.z - mean); q += (v1.w - mean) * (v1.w - mean);
    q = wave_sum(q);
    if (lane == 0) red[wid] = q;
    __syncthreads();
    float inv = rsqrtf((red[0] + red[1] + red[2] + red[3]) * (1.0f / E) + 1e-5f);
    int e = tid * 8;
    float4 w0 = *reinterpret_cast<const float4*>(w + e);
    float4 w1 = *reinterpret_cast<const float4*>(w + e + 4);
    float4 b0 = *reinterpret_cast<const float4*>(b + e);
    float4 b1 = *reinterpret_cast<const float4*>(b + e + 4);
    float4 o0, o1;
    o0.x = (v0.x - mean) * inv * w0.x + b0.x; o0.y = (v0.y - mean) * inv * w0.y + b0.y;
    o0.z = (v0.z - mean) * inv * w0.z + b0.z; o0.w = (v0.w - mean) * inv * w0.w + b0.w;
    o1.x = (v1.x - mean) * inv * w1.x + b1.x; o1.y = (v1.y - mean) * inv * w1.y + b1.y;
    o1.z = (v1.z - mean) * inv * w1.z + b1.z; o1.w = (v1.w - mean) * inv * w1.w + b1.w;
    float* op = out + (size_t)row * E + e;
    *reinterpret_cast<float4*>(op) = o0;
    *reinterpret_cast<float4*>(op + 4) = o1;
}

// mk = bf16(xa + sx*maa_x), sx recomputed inline (time-mix shift, state row 1)
__global__ __launch_bounds__(256) void k_mk(const float* __restrict__ xa,
                                            const float* __restrict__ state,
                                            const float* __restrict__ maa_x,
                                            u16* __restrict__ out) {
    int i = (blockIdx.x * 256 + threadIdx.x) * 4;
    if (i >= NBLE) return;
    int n = i >> 11, e = i & (E - 1);
    int l = n & (LL - 1), b = n >> 10;
    float4 cur = *reinterpret_cast<const float4*>(xa + i);
    float4 prev;
    if (l > 0) prev = *reinterpret_cast<const float4*>(xa + i - E);
    else       prev = *reinterpret_cast<const float4*>(state + (size_t)b * 66 * E + E + e);
    float4 m = *reinterpret_cast<const float4*>(maa_x + e);
    ushort4 o = make_ushort4(f2b(cur.x + (prev.x - cur.x) * m.x),
                             f2b(cur.y + (prev.y - cur.y) * m.y),
                             f2b(cur.z + (prev.z - cur.z) * m.z),
                             f2b(cur.w + (prev.w - cur.w) * m.w));
    *reinterpret_cast<ushort4*>(out + i) = o;
}

// channel-mix token shift (state row 0) + two mixes -> bf16
__global__ __launch_bounds__(256) void k_mix2(const float* __restrict__ xc,
                                              const float* __restrict__ state,
                                              const float* __restrict__ mk,
                                              const float* __restrict__ mr,
                                              u16* __restrict__ xk2,
                                              u16* __restrict__ xr2) {
    int i = (blockIdx.x * 256 + threadIdx.x) * 4;
    if (i >= NBLE) return;
    int n = i >> 11, e = i & (E - 1);
    int l = n & (LL - 1), b = n >> 10;
    float4 cur = *reinterpret_cast<const float4*>(xc + i);
    float4 prev;
    if (l > 0) prev = *reinterpret_cast<const float4*>(xc + i - E);
    else       prev = *reinterpret_cast<const float4*>(state + (size_t)b * 66 * E + e);
    float4 sx = make_float4(prev.x - cur.x, prev.y - cur.y, prev.z - cur.z, prev.w - cur.w);
    float4 k4 = *reinterpret_cast<const float4*>(mk + e);
    float4 r4 = *reinterpret_cast<const float4*>(mr + e);
    ushort4 ok = make_ushort4(f2b(cur.x + sx.x * k4.x), f2b(cur.y + sx.y * k4.y),
                              f2b(cur.z + sx.z * k4.z), f2b(cur.w + sx.w * k4.w));
    ushort4 orr = make_ushort4(f2b(cur.x + sx.x * r4.x), f2b(cur.y + sx.y * r4.y),
                               f2b(cur.z + sx.z * r4.z), f2b(cur.w + sx.w * r4.w));
    *reinterpret_cast<ushort4*>(xk2 + i) = ok;
    *reinterpret_cast<ushort4*>(xr2 + i) = orr;
}

// per-head groupnorm over S=64, *gn_w+gn_b, *g (bf16, in-place ok) -> bf16
__global__ __launch_bounds__(256) void k_gnorm(const float* __restrict__ wkv,
                                               const u16* __restrict__ g,
                                               const float* __restrict__ gw,
                                               const float* __restrict__ gb,
                                               u16* __restrict__ ogg) {
    int gidx = blockIdx.x * 4 + (threadIdx.x >> 6);
    int lane = threadIdx.x & 63;
    int n = gidx >> 5, h = gidx & 31;
    size_t base = (size_t)n * E + h * SSS;
    float v = wkv[base + lane];
    float mean = wave_sum(v) * (1.0f / SSS);
    float d = v - mean;
    float var = wave_sum(d * d) * (1.0f / SSS);
    float norm = d * rsqrtf(var + 1e-5f);
    int e = h * SSS + lane;
    float res = norm * gw[e] + gb[e];
    float gv = b2f(g[base + lane]);
    ogg[base + lane] = f2b(res * gv);
}

// ---------------- WKV sequential scan (chunked LDS pipeline) ----------
// grid = B*H*2 = 256 blocks of 512 (8 waves, 2/SIMD).  Block = (b,h,jh).
// Wave handles 4 j-columns x full i: lane = ig*4 + jl, lane owns 4 state
// rows.  16-timestep chunks staged to LDS via global_load_lds, double
// buffered, one barrier per chunk.  Reduction over ig via 4 shfl_xor.
#define CT 16

__global__ __launch_bounds__(512) void k_scan(const u16* __restrict__ Rb,
                                              const u16* __restrict__ Kb,
                                              const u16* __restrict__ Vb,
                                              const float* __restrict__ W,
                                              const float* __restrict__ state,
                                              const float* __restrict__ u,
                                              float* __restrict__ out) {
    __shared__ u16   ldsR[2][CT * 64];
    __shared__ u16   ldsK[2][CT * 64];
    __shared__ float ldsW[2][CT * 64];
    __shared__ u16   ldsV[2][CT * 32];
    const int blk = blockIdx.x;
    const int b = blk >> 6;
    const int rem = blk & 63;
    const int h = rem >> 1, jh = rem & 1;
    const int tid = threadIdx.x;
    const int wvid = tid >> 6;       // 0..7
    const int lane = tid & 63;
    const int ig = lane >> 2;        // 0..15
    const int jl = lane & 3;
    const int jv = wvid * 4 + jl;    // 0..31
    const int j  = jh * 32 + jv;
    const int i0 = ig * 4;
    float s[4], uu[4];
    const float* s0 = state + (size_t)b * 66 * E + 2 * E + h * (SSS * SSS);
#pragma unroll
    for (int ii = 0; ii < 4; ii++) {
        s[ii] = s0[(i0 + ii) * SSS + j];
        uu[ii] = u[h * SSS + i0 + ii];
    }
    const size_t off0 = (size_t)b * LL * E + h * SSS;

    // staging lambda: chunk c -> buffer bufsel (each wave a fixed subset)
    auto stage = [&](int c, int bufsel) {
        size_t base = off0 + (size_t)c * CT * E;
        if (wvid == 0) {
            const u16* g0 = Rb + base + (size_t)(lane >> 3) * E + ((lane & 7) << 3);
            gl_lds16(g0,         &ldsR[bufsel][lane * 8]);
            gl_lds16(g0 + 8 * E, &ldsR[bufsel][512 + lane * 8]);
        } else if (wvid == 1) {
            const u16* g0 = Kb + base + (size_t)(lane >> 3) * E + ((lane & 7) << 3);
            gl_lds16(g0,         &ldsK[bufsel][lane * 8]);
            gl_lds16(g0 + 8 * E, &ldsK[bufsel][512 + lane * 8]);
        } else if (wvid == 2) {
            const float* g0 = W + base + (size_t)(lane >> 4) * E + ((lane & 15) << 2);
            gl_lds16(g0,         &ldsW[bufsel][lane * 4]);
            gl_lds16(g0 + 4 * E, &ldsW[bufsel][256 + lane * 4]);
        } else if (wvid == 3) {
            const float* g0 = W + base + (size_t)(8 + (lane >> 4)) * E + ((lane & 15) << 2);
            gl_lds16(g0,         &ldsW[bufsel][512 + lane * 4]);
            gl_lds16(g0 + 4 * E, &ldsW[bufsel][768 + lane * 4]);
        } else if (wvid == 4) {
            const u16* g0 = Vb + base + (size_t)(lane >> 2) * E + jh * 32 + ((lane & 3) << 3);
            gl_lds16(g0, &ldsV[bufsel][lane * 8]);
        }
    };

    stage(0, 0);
    __syncthreads();
    int cur = 0;
    for (int c = 0; c < LL / CT; c++) {
        if (c + 1 < LL / CT) stage(c + 1, cur ^ 1);
        size_t offt = off0 + (size_t)c * CT * E + j;
#pragma unroll
        for (int tt = 0; tt < CT; tt++) {
            ushort4 rv = *reinterpret_cast<const ushort4*>(&ldsR[cur][tt * 64 + i0]);
            ushort4 kv = *reinterpret_cast<const ushort4*>(&ldsK[cur][tt * 64 + i0]);
            float4  wv = *reinterpret_cast<const float4*>(&ldsW[cur][tt * 64 + i0]);
            float vj = b2f(ldsV[cur][tt * 32 + jv]);
            float acc = 0.f, a;
            a = b2f(kv.x) * vj; acc += b2f(rv.x) * fmaf(uu[0], a, s[0]); s[0] = fmaf(wv.x, s[0], a);
            a = b2f(kv.y) * vj; acc += b2f(rv.y) * fmaf(uu[1], a, s[1]); s[1] = fmaf(wv.y, s[1], a);
            a = b2f(kv.z) * vj; acc += b2f(rv.z) * fmaf(uu[2], a, s[2]); s[2] = fmaf(wv.z, s[2], a);
            a = b2f(kv.w) * vj; acc += b2f(rv.w) * fmaf(uu[3], a, s[3]); s[3] = fmaf(wv.w, s[3], a);
            acc += __shfl_xor(acc, 4, 64);
            acc += __shfl_xor(acc, 8, 64);
            acc += __shfl_xor(acc, 16, 64);
            acc += __shfl_xor(acc, 32, 64);
            if (ig == 0) out[offt + (size_t)tt * E] = acc;
        }
        __syncthreads();
        cur ^= 1;
    }
}

// ---------------- 128x128 MFMA GEMM (m97 structure), N=2048, M=4096 ----------
// C[4096,2048] = ep( A[4096,K](bf16,lda) * Bw[2048,K](bf16)^T )
// global_load_lds width-16 staging, XOR bank swizzle on the global source side.
// EP: 2 xm(bf16) 3 decay(f32) 5 emat1+acc(f32) 6 sigmoid(f32) 7 relu^2(bf16)
//     8 emat1+emat2*acc(f32) 9 plain bf16 10 silu bf16
template <int EP>
__global__ __launch_bounds__(256) void k_gemm128(const u16* __restrict__ A, int lda,
                                                 const u16* __restrict__ Bw,
                                                 void* __restrict__ C, int K,
                                                 const float* __restrict__ evec,
                                                 const float* __restrict__ emat1,
                                                 const float* __restrict__ emat2) {
    __shared__ u16 As[128 * 32];
    __shared__ u16 Bs[128 * 32];
    const int tid = threadIdx.x;
    const int m0 = blockIdx.y << 7, n0 = blockIdx.x << 7;
    const int srow = tid >> 2;                                  // 0..63
    const int scol = (((tid & 3) ^ ((srow >> 1) & 3)) << 3);    // swizzled global chunk
    const int wv = tid >> 6, lane = tid & 63;
    const int wy = (wv >> 1) << 6, wx = (wv & 1) << 6;
    const int lr = lane & 15, lq = lane >> 4;
    const int cofs = ((lq ^ ((lr >> 1) & 3)) << 3);             // swizzled LDS chunk
    f32x4 acc[4][4];
#pragma unroll
    for (int a = 0; a < 4; a++)
#pragma unroll
        for (int bq = 0; bq < 4; bq++) acc[a][bq] = {0.f, 0.f, 0.f, 0.f};
    const u16* gA = A + (size_t)(m0 + srow) * lda + scol;
    const u16* gB = Bw + (size_t)(n0 + srow) * K + scol;
    u16* lA = As + srow * 32 + ((tid & 3) << 3);
    u16* lB = Bs + srow * 32 + ((tid & 3) << 3);
    for (int k0 = 0; k0 < K; k0 += 32) {
        gl_lds16(gA + k0, lA);
        gl_lds16(gA + (size_t)64 * lda + k0, lA + 64 * 32);
        gl_lds16(gB + k0, lB);
        gl_lds16(gB + (size_t)64 * K + k0, lB + 64 * 32);
        __syncthreads();     // drains vmcnt (compiler) -> LDS tiles ready
        bf16x8 af[4], bfr[4];
#pragma unroll
        for (int mt = 0; mt < 4; mt++)
            af[mt] = *reinterpret_cast<const bf16x8*>(As + (wy + mt * 16 + lr) * 32 + cofs);
#pragma unroll
        for (int nt = 0; nt < 4; nt++)
            bfr[nt] = *reinterpret_cast<const bf16x8*>(Bs + (wx + nt * 16 + lr) * 32 + cofs);
#pragma unroll
        for (int mt = 0; mt < 4; mt++)
#pragma unroll
            for (int nt = 0; nt < 4; nt++)
                acc[mt][nt] = __builtin_amdgcn_mfma_f32_16x16x32_bf16(af[mt], bfr[nt], acc[mt][nt], 0, 0, 0);
        __syncthreads();     // protect LDS before next iteration's staging
    }
    const int gmb = m0 + wy + (lq << 2);
    const int gnb = n0 + wx + lr;
#pragma unroll
    for (int mt = 0; mt < 4; mt++) {
#pragma unroll
        for (int nt = 0; nt < 4; nt++) {
            int gn = gnb + nt * 16;
#pragma unroll
            for (int i = 0; i < 4; i++) {
                int gm = gmb + mt * 16 + i;
                size_t idx = (size_t)gm * E + gn;
                float v = acc[mt][nt][i];
                if constexpr (EP == 2) {
                    int l = gm & (LL - 1), bb = gm >> 10;
                    float cur = emat1[idx];
                    float prev = (l > 0) ? emat1[idx - E]
                                         : emat2[(size_t)bb * 66 * E + E + gn];
                    ((u16*)C)[idx] = f2b(cur + (prev - cur) * (evec[gn] + v));
                }
                else if constexpr (EP == 3) ((float*)C)[idx] = expf(-expf(evec[gn] + v));
                else if constexpr (EP == 5) ((float*)C)[idx] = emat1[idx] + v;
                else if constexpr (EP == 6) ((float*)C)[idx] = 1.f / (1.f + expf(-v));
                else if constexpr (EP == 7) { float t = fmaxf(v, 0.f); ((u16*)C)[idx] = f2b(t * t); }
                else if constexpr (EP == 8) ((float*)C)[idx] = emat1[idx] + emat2[idx] * v;
                else if constexpr (EP == 9) ((u16*)C)[idx] = f2b(v);
                else if constexpr (EP == 10) { float sg = 1.f / (1.f + expf(-v)); ((u16*)C)[idx] = f2b(v * sg); }
            }
        }
    }
}

// ---------------- 64-tile GEMM (odd N: 160 / 64), EP1 = tanh bf16 -----------
#define BK  32
#define LDP 40

template <int EP>
__global__ __launch_bounds__(256) void k_gemm(const u16* __restrict__ A, int lda,
                                              const u16* __restrict__ Bw,
                                              void* __restrict__ C,
                                              int M, int N, int K) {
    __shared__ u16 As[64 * LDP];
    __shared__ u16 Bs[64 * LDP];
    const int tid = threadIdx.x;
    const int m0 = blockIdx.y << 6, n0 = blockIdx.x << 6;
    const int srow = tid >> 2, skc = (tid & 3) << 3;
    const int lane = tid & 63, wv = tid >> 6;
    const int wr = (wv >> 1) << 5, wc = (wv & 1) << 5;
    const int lr = lane & 15, lq = lane >> 4;
    f32x4 acc[2][2];
#pragma unroll
    for (int a = 0; a < 2; a++)
#pragma unroll
        for (int bq = 0; bq < 2; bq++) acc[a][bq] = {0.f, 0.f, 0.f, 0.f};
    const u16* aptr = A + (size_t)(m0 + srow) * lda + skc;
    const u16* bptr = Bw + (size_t)(n0 + srow) * K + skc;
    const bool bvalid = (n0 + srow) < N;
    for (int k0 = 0; k0 < K; k0 += BK) {
        float4 av = *reinterpret_cast<const float4*>(aptr + k0);
        float4 bv = bvalid ? *reinterpret_cast<const float4*>(bptr + k0)
                           : make_float4(0.f, 0.f, 0.f, 0.f);
        __syncthreads();
        *reinterpret_cast<float4*>(As + srow * LDP + skc) = av;
        *reinterpret_cast<float4*>(Bs + srow * LDP + skc) = bv;
        __syncthreads();
        bf16x8 a0 = *reinterpret_cast<const bf16x8*>(As + (wr + lr) * LDP + lq * 8);
        bf16x8 a1 = *reinterpret_cast<const bf16x8*>(As + (wr + 16 + lr) * LDP + lq * 8);
        bf16x8 b0 = *reinterpret_cast<const bf16x8*>(Bs + (wc + lr) * LDP + lq * 8);
        bf16x8 b1 = *reinterpret_cast<const bf16x8*>(Bs + (wc + 16 + lr) * LDP + lq * 8);
        acc[0][0] = __builtin_amdgcn_mfma_f32_16x16x32_bf16(a0, b0, acc[0][0], 0, 0, 0);
        acc[0][1] = __builtin_amdgcn_mfma_f32_16x16x32_bf16(a0, b1, acc[0][1], 0, 0, 0);
        acc[1][0] = __builtin_amdgcn_mfma_f32_16x16x32_bf16(a1, b0, acc[1][0], 0, 0, 0);
        acc[1][1] = __builtin_amdgcn_mfma_f32_16x16x32_bf16(a1, b1, acc[1][1], 0, 0, 0);
    }
    const int gmb = m0 + wr + lq * 4;
    const int gnb = n0 + wc + lr;
#pragma unroll
    for (int mi = 0; mi < 2; mi++) {
#pragma unroll
        for (int ni = 0; ni < 2; ni++) {
            int gn = gnb + ni * 16;
            if (gn >= N) continue;
#pragma unroll
            for (int i = 0; i < 4; i++) {
                int gm = gmb + mi * 16 + i;
                size_t idx = (size_t)gm * N + gn;
                float v = acc[mi][ni][i];
                if constexpr (EP == 1) ((u16*)C)[idx] = f2b(tanhf(v));
            }
        }
    }
}

// ---------------- launch ----------------

extern "C" void kernel_launch(void* const* d_in, const int* in_sizes, int n_in,
                              void* d_out, int out_size, void* d_ws, size_t ws_size,
                              hipStream_t stream) {
    const float* x          = (const float*)d_in[0];
    const float* state      = (const float*)d_in[1];
    const float* ln1_w      = (const float*)d_in[2];
    const float* ln1_b      = (const float*)d_in[3];
    const float* ln2_w      = (const float*)d_in[4];
    const float* ln2_b      = (const float*)d_in[5];
    const float* maa_x      = (const float*)d_in[6];
    const float* maa_w1     = (const float*)d_in[7];
    const float* maa_w2     = (const float*)d_in[8];
    const float* maa_stack  = (const float*)d_in[9];
    const float* time_decay = (const float*)d_in[10];
    const float* td_w1      = (const float*)d_in[11];
    const float* td_w2      = (const float*)d_in[12];
    const float* u          = (const float*)d_in[13];
    const float* Wr         = (const float*)d_in[14];
    const float* Wk         = (const float*)d_in[15];
    const float* Wv         = (const float*)d_in[16];
    const float* Wg         = (const float*)d_in[17];
    const float* Wo         = (const float*)d_in[18];
    const float* gn_w       = (const float*)d_in[19];
    const float* gn_b       = (const float*)d_in[20];
    const float* ffn_k      = (const float*)d_in[21];
    const float* ffn_r      = (const float*)d_in[22];
    const float* Wfk        = (const float*)d_in[23];
    const float* Wfr        = (const float*)d_in[24];
    const float* Wfv        = (const float*)d_in[25];

    char* ws = (char*)d_ws;
    float* R0 = (float*)(ws);                        // xa -> wkv -> x1   (32 MiB f32)
    float* R1 = (float*)(ws + 33554432);             // Wdecay -> xc -> rr (32 MiB f32)
    u16*   R2 = (u16*)(ws + 67108864);               // mk/xm slot -> xk2 (16 MiB bf16)
    u16*   R3 = (u16*)(ws + 83886080);               // Rb -> xr2
    u16*   R4 = (u16*)(ws + 100663296);              // Kb -> kk
    u16*   R5 = (u16*)(ws + 117440512);              // Vb
    u16*   R6 = (u16*)(ws + 134217728);              // g -> ogg
    u16*   WB = (u16*)(ws + 150994944);              // weight bf16 slot (8 MiB)
    u16*   Hx = (u16*)(ws + 159383552);              // tanh(mk@w1)  NBL x 160
    u16*   Ht = (u16*)(ws + 160694272);              // tanh(xw@td1) NBL x 64
    u16*  WT1 = (u16*)(ws + 161218560);              // maa_w1^T  160 x 2048
    u16*  WT2 = (u16*)(ws + 161873920);              // maa_w2^T  5 x (2048 x 32)
    u16*  WT3 = (u16*)(ws + 162529280);              // td_w1^T   64 x 2048
    u16*  WT4 = (u16*)(ws + 162791424);              // td_w2^T   2048 x 64

    dim3 blk(256);
    dim3 g128(16, 32);          // N=2048/128, M=4096/128
    dim3 g160(3, 64), g64(1, 64);
    const int ncv = (E * E / 4) / 256;
    const int nel = NBLE / 1024;

    // small-weight transposes (to (N,K) bf16)
    k_transpose<<<(E * 160 + 255) / 256, blk, 0, stream>>>(maa_w1, WT1, E, 160);
    for (int f = 0; f < 5; f++)
        k_transpose<<<(32 * E + 255) / 256, blk, 0, stream>>>(maa_w2 + f * 32 * E, WT2 + f * E * 32, 32, E);
    k_transpose<<<(E * 64 + 255) / 256, blk, 0, stream>>>(td_w1, WT3, E, 64);
    k_transpose<<<(64 * E + 255) / 256, blk, 0, stream>>>(td_w2, WT4, 64, E);

    // time-mix front end
    k_ln<<<NBL, blk, 0, stream>>>(x, ln1_w, ln1_b, R0);                    // xa
    k_mk<<<nel, blk, 0, stream>>>(R0, state, maa_x, R2);                   // mk bf16
    k_gemm<1><<<g160, blk, 0, stream>>>(R2, E, WT1, Hx, NBL, 160, E);

    // decay chain (f=1: w)
    k_gemm128<2><<<g128, blk, 0, stream>>>(Hx + 1 * 32, 160, WT2 + 1 * E * 32, R2, 32,
                                           maa_stack + 1 * E, R0, state);
    k_gemm<1><<<g64, blk, 0, stream>>>(R2, E, WT3, Ht, NBL, 64, E);
    k_gemm128<3><<<g128, blk, 0, stream>>>(Ht, 64, WT4, R1, 64, time_decay, nullptr, nullptr);

    // k projection (f=0)
    k_gemm128<2><<<g128, blk, 0, stream>>>(Hx + 0 * 32, 160, WT2 + 0 * E * 32, R2, 32,
                                           maa_stack + 0 * E, R0, state);
    k_convert<<<ncv, blk, 0, stream>>>(Wk, WB, E * E);
    k_gemm128<9><<<g128, blk, 0, stream>>>(R2, E, WB, R4, E, nullptr, nullptr, nullptr);

    // v projection (f=2)
    k_gemm128<2><<<g128, blk, 0, stream>>>(Hx + 2 * 32, 160, WT2 + 2 * E * 32, R2, 32,
                                           maa_stack + 2 * E, R0, state);
    k_convert<<<ncv, blk, 0, stream>>>(Wv, WB, E * E);
    k_gemm128<9><<<g128, blk, 0, stream>>>(R2, E, WB, R5, E, nullptr, nullptr, nullptr);

    // g projection (f=4)
    k_gemm128<2><<<g128, blk, 0, stream>>>(Hx + 4 * 32, 160, WT2 + 4 * E * 32, R2, 32,
                                           maa_stack + 4 * E, R0, state);
    k_convert<<<ncv, blk, 0, stream>>>(Wg, WB, E * E);
    k_gemm128<10><<<g128, blk, 0, stream>>>(R2, E, WB, R6, E, nullptr, nullptr, nullptr);

    // r projection (f=3) — last use of xa (R0)
    k_gemm128<2><<<g128, blk, 0, stream>>>(Hx + 3 * 32, 160, WT2 + 3 * E * 32, R2, 32,
                                           maa_stack + 3 * E, R0, state);
    k_convert<<<ncv, blk, 0, stream>>>(Wr, WB, E * E);
    k_gemm128<9><<<g128, blk, 0, stream>>>(R2, E, WB, R3, E, nullptr, nullptr, nullptr);

    // sequential WKV scan -> R0 (wkv f32), then groupnorm * g -> ogg (R6 in place)
    k_scan<<<256, dim3(512), 0, stream>>>(R3, R4, R5, R1, state, u, R0);
    k_gnorm<<<NBL * HHH / 4, blk, 0, stream>>>(R0, R6, gn_w, gn_b, R6);

    // output projection + residual -> x1 (R0; wkv dead)
    k_convert<<<ncv, blk, 0, stream>>>(Wo, WB, E * E);
    k_gemm128<5><<<g128, blk, 0, stream>>>(R6, E, WB, R0, E, nullptr, x, nullptr);

    // channel mix
    k_ln<<<NBL, blk, 0, stream>>>(R0, ln2_w, ln2_b, R1);                   // xc
    k_mix2<<<nel, blk, 0, stream>>>(R1, state, ffn_k, ffn_r, R2, R3);      // xk2, xr2
    k_convert<<<ncv, blk, 0, stream>>>(Wfk, WB, E * E);
    k_gemm128<7><<<g128, blk, 0, stream>>>(R2, E, WB, R4, E, nullptr, nullptr, nullptr);
    k_convert<<<ncv, blk, 0, stream>>>(Wfr, WB, E * E);
    k_gemm128<6><<<g128, blk, 0, stream>>>(R3, E, WB, R1, E, nullptr, nullptr, nullptr);
    k_convert<<<ncv, blk, 0, stream>>>(Wfv, WB, E * E);
    k_gemm128<8><<<g128, blk, 0, stream>>>(R4, E, WB, (float*)d_out, E, nullptr, R0, R1);
}